// Round 1
// baseline (2946.835 us; speedup 1.0000x reference)
//
#include <hip/hip_runtime.h>

typedef unsigned int uint;
typedef unsigned short ushort;

#define N_PTS 4096
#define B_SZ 16
#define M_PTS 1024
#define K_SMP 32
#define NROWS (B_SZ*M_PTS*K_SMP)   /* 524288 */
#define INV_CNT (1.0f/524288.0f)   /* exact: 2^-19 */

// ---------- helpers ----------
__device__ __forceinline__ float sqdist3(float ax,float ay,float az,float bx,float by,float bz){
  // exact-match of numpy/XLA f32: separate sub/mul/add, no FMA contraction
  float dx=__fsub_rn(ax,bx), dy=__fsub_rn(ay,by), dz=__fsub_rn(az,bz);
  return __fadd_rn(__fadd_rn(__fmul_rn(dx,dx),__fmul_rn(dy,dy)),__fmul_rn(dz,dz));
}
__device__ __forceinline__ ushort f2bf(float x){
  uint u = __float_as_uint(x);
  u = (u + 0x7fffu + ((u>>16)&1u)) >> 16;   // RNE
  return (ushort)u;
}
__device__ __forceinline__ float bf2f(uint u){ return __uint_as_float(u<<16); }

// ---------- 1. farthest point sampling (exact f32) ----------
// one block per batch; 512 threads, 8 points/thread (contiguous for tie order)
__global__ __launch_bounds__(512) void fps_kernel(const float* __restrict__ xyz,
                                                  float* __restrict__ out_newxyz){
  const int b = blockIdx.x;
  const int t = threadIdx.x;
  __shared__ float sx[N_PTS], sy[N_PTS], sz[N_PTS];
  __shared__ float rv[2][8];
  __shared__ int   ri[2][8];
  const float* src = xyz + (size_t)b*N_PTS*3;
  for (int i = t; i < N_PTS*3; i += 512){
    float v = src[i];
    int p = i/3, j = i%3;
    (j==0?sx:(j==1?sy:sz))[p] = v;
  }
  __syncthreads();
  float px[8], py[8], pz[8], dist[8];
  const int p0 = t*8;
#pragma unroll
  for (int i=0;i<8;i++){ px[i]=sx[p0+i]; py[i]=sy[p0+i]; pz[i]=sz[p0+i]; dist[i]=1e10f; }
  int f = 0;
  const int w = t >> 6, lane = t & 63;
  float* outx = out_newxyz + (size_t)b*M_PTS*3;
  for (int s = 0; s < M_PTS; ++s){
    float cx = sx[f], cy = sy[f], cz = sz[f];
    if (t == 0){ outx[s*3+0]=cx; outx[s*3+1]=cy; outx[s*3+2]=cz; }
    float m = -1.0f; int mi = p0;
#pragma unroll
    for (int i=0;i<8;i++){
      float d  = sqdist3(px[i],py[i],pz[i],cx,cy,cz);
      float nd = fminf(dist[i], d);
      dist[i] = nd;
      if (nd > m){ m = nd; mi = p0+i; }   // strict > keeps first (lowest) index
    }
#pragma unroll
    for (int off=1; off<64; off<<=1){
      float om = __shfl_xor(m, off);
      int   oi = __shfl_xor(mi, off);
      if (om > m || (om == m && oi < mi)){ m = om; mi = oi; }
    }
    const int par = s & 1;
    if (lane == 0){ rv[par][w] = m; ri[par][w] = mi; }
    __syncthreads();
    float bm_ = rv[par][0]; int bi = ri[par][0];
#pragma unroll
    for (int q=1;q<8;q++){
      float qv = rv[par][q]; int qi = ri[par][q];
      if (qv > bm_ || (qv == bm_ && qi < bi)){ bm_ = qv; bi = qi; }
    }
    f = bi;
  }
}

// ---------- 2. ball query (exact f32, first-32 in index order) ----------
// 1024 blocks; block = 4 waves handles 16 centroids of one batch
__global__ __launch_bounds__(256) void ballq_kernel(const float* __restrict__ xyz,
                                                    const float* __restrict__ newxyz,
                                                    int* __restrict__ gidx){
  const int blk = blockIdx.x;
  const int b = blk >> 6;
  const int mbase = (blk & 63) * 16;
  __shared__ float sx[N_PTS], sy[N_PTS], sz[N_PTS];
  const float* src = xyz + (size_t)b*N_PTS*3;
  for (int i = threadIdx.x; i < N_PTS*3; i += 256){
    float v = src[i]; int p = i/3, j = i%3;
    (j==0?sx:(j==1?sy:sz))[p] = v;
  }
  __syncthreads();
  const int w = threadIdx.x >> 6, lane = threadIdx.x & 63;
  const float R2 = (float)(0.2*0.2);   // f32(f64 product) — matches reference cast
  for (int mm = w; mm < 16; mm += 4){
    const int m = mbase + mm;
    const float* c = newxyz + ((size_t)b*M_PTS + m)*3;
    float cx = c[0], cy = c[1], cz = c[2];
    int* gout = gidx + ((size_t)b*M_PTS + m)*K_SMP;
    int cnt = 0;
    for (int base = 0; base < N_PTS && cnt < K_SMP; base += 64){
      int p = base + lane;
      float d = sqdist3(sx[p],sy[p],sz[p],cx,cy,cz);
      bool in = (d <= R2);
      unsigned long long mask = __ballot(in);
      int prefix = __popcll(mask & ((1ull << lane) - 1ull));
      int slot = cnt + prefix;
      if (in && slot < K_SMP) gout[slot] = p;
      cnt += __popcll(mask);
    }
    if (cnt < K_SMP){
      int slot = cnt + lane;
      if (slot < K_SMP) gout[slot] = 0;
    }
  }
}

// ---------- 3. conv0: gather + concat + 67->64 matmul (+bias), write bf16 ----------
__global__ __launch_bounds__(256) void conv0_kernel(const float* __restrict__ xyz,
                                                    const float* __restrict__ points,
                                                    const float* __restrict__ newxyz,
                                                    const int* __restrict__ gidx,
                                                    const float* __restrict__ W0,
                                                    const float* __restrict__ b0,
                                                    ushort* __restrict__ x1){
  const int r = blockIdx.x*256 + threadIdx.x;         // 524288 rows
  const int b = r >> 15, m = (r >> 5) & 1023;
  const int g = gidx[r];
  const float* pc = newxyz + ((size_t)(b<<10) + m)*3;
  const float* pp = xyz    + ((size_t)(b<<12) + g)*3;
  float f[67];
  f[0]=pp[0]-pc[0]; f[1]=pp[1]-pc[1]; f[2]=pp[2]-pc[2];
  const float4* prow = (const float4*)(points + (((size_t)(b<<12) + g) << 6));
#pragma unroll
  for (int q=0;q<16;q++){
    float4 v = prow[q];
    f[3+4*q]=v.x; f[4+4*q]=v.y; f[5+4*q]=v.z; f[6+4*q]=v.w;
  }
  float acc[64];
#pragma unroll
  for (int o=0;o<64;o++) acc[o]=b0[o];
#pragma unroll
  for (int o=0;o<64;o++){
    const float* wr = W0 + o*67;
    float a = acc[o];
#pragma unroll
    for (int c=0;c<67;c++) a = fmaf(f[c], wr[c], a);
    acc[o]=a;
  }
  uint4* orow = (uint4*)(x1 + ((size_t)r << 6));
#pragma unroll
  for (int q=0;q<8;q++){
    uint4 v;
    v.x = (uint)f2bf(acc[q*8+0]) | ((uint)f2bf(acc[q*8+1])<<16);
    v.y = (uint)f2bf(acc[q*8+2]) | ((uint)f2bf(acc[q*8+3])<<16);
    v.z = (uint)f2bf(acc[q*8+4]) | ((uint)f2bf(acc[q*8+5])<<16);
    v.w = (uint)f2bf(acc[q*8+6]) | ((uint)f2bf(acc[q*8+7])<<16);
    orow[q]=v;
  }
}

// ---------- stats: per-channel sum & sumsq over all rows ----------
template<int C>
__global__ __launch_bounds__(256) void stats_kernel(const ushort* __restrict__ x,
                                                    float* __restrict__ S,
                                                    float* __restrict__ SS){
  constexpr int RL = 256 / C;
  const int c  = threadIdx.x % C;
  const int rl = threadIdx.x / C;
  const int rows_per_block = NROWS / 256;   // gridDim = 256
  const int r0 = blockIdx.x * rows_per_block;
  const int r1 = r0 + rows_per_block;
  float s = 0.f, ss = 0.f;
  for (int r = r0 + rl; r < r1; r += RL){
    float v = bf2f((uint)x[(size_t)r*C + c]);
    s += v; ss = fmaf(v, v, ss);
  }
  __shared__ float ls[256], lss[256];
  ls[threadIdx.x] = s; lss[threadIdx.x] = ss;
  __syncthreads();
  if (threadIdx.x < C){
    float a = 0.f, q2 = 0.f;
#pragma unroll
    for (int q = 0; q < RL; q++){ a += ls[q*C + c]; q2 += lss[q*C + c]; }
    atomicAdd(&S[c], a); atomicAdd(&SS[c], q2);
  }
}

// ---------- conv1: BN0+ReLU fused on read, 64->64 ----------
__global__ __launch_bounds__(256) void conv1_kernel(const ushort* __restrict__ x1,
                                                    const float* __restrict__ S0,
                                                    const float* __restrict__ SS0,
                                                    const float* __restrict__ g0,
                                                    const float* __restrict__ be0,
                                                    const float* __restrict__ W1,
                                                    const float* __restrict__ b1,
                                                    ushort* __restrict__ x2){
  __shared__ float sc[64], sh[64];
  if (threadIdx.x < 64){
    int c = threadIdx.x;
    float mean = S0[c]*INV_CNT;
    float var  = fmaf(-mean, mean, SS0[c]*INV_CNT);
    float is   = rsqrtf(var + 1e-5f);
    float scv  = g0[c]*is;
    sc[c] = scv; sh[c] = fmaf(-mean, scv, be0[c]);
  }
  __syncthreads();
  const size_t r = (size_t)blockIdx.x*256 + threadIdx.x;
  const uint4* row = (const uint4*)(x1 + (r<<6));
  float f[64];
#pragma unroll
  for (int q=0;q<8;q++){
    uint4 v = row[q];
    f[q*8+0]=bf2f(v.x&0xffffu); f[q*8+1]=bf2f(v.x>>16);
    f[q*8+2]=bf2f(v.y&0xffffu); f[q*8+3]=bf2f(v.y>>16);
    f[q*8+4]=bf2f(v.z&0xffffu); f[q*8+5]=bf2f(v.z>>16);
    f[q*8+6]=bf2f(v.w&0xffffu); f[q*8+7]=bf2f(v.w>>16);
  }
#pragma unroll
  for (int c=0;c<64;c++) f[c] = fmaxf(fmaf(f[c], sc[c], sh[c]), 0.f);
  float acc[64];
#pragma unroll
  for (int o=0;o<64;o++) acc[o]=b1[o];
#pragma unroll
  for (int o=0;o<64;o++){
    const float* wr = W1 + o*64;
    float a = acc[o];
#pragma unroll
    for (int c=0;c<64;c++) a = fmaf(f[c], wr[c], a);
    acc[o]=a;
  }
  uint4* orow = (uint4*)(x2 + (r<<6));
#pragma unroll
  for (int q=0;q<8;q++){
    uint4 v;
    v.x = (uint)f2bf(acc[q*8+0]) | ((uint)f2bf(acc[q*8+1])<<16);
    v.y = (uint)f2bf(acc[q*8+2]) | ((uint)f2bf(acc[q*8+3])<<16);
    v.z = (uint)f2bf(acc[q*8+4]) | ((uint)f2bf(acc[q*8+5])<<16);
    v.w = (uint)f2bf(acc[q*8+6]) | ((uint)f2bf(acc[q*8+7])<<16);
    orow[q]=v;
  }
}

// ---------- conv2: BN1+ReLU fused on read, 64->128 (2 waves share a row set) ----------
__global__ __launch_bounds__(256) void conv2_kernel(const ushort* __restrict__ x2,
                                                    const float* __restrict__ S1,
                                                    const float* __restrict__ SS1,
                                                    const float* __restrict__ g1,
                                                    const float* __restrict__ be1,
                                                    const float* __restrict__ W2,
                                                    const float* __restrict__ b2,
                                                    ushort* __restrict__ x3){
  __shared__ float sc[64], sh[64];
  if (threadIdx.x < 64){
    int c = threadIdx.x;
    float mean = S1[c]*INV_CNT;
    float var  = fmaf(-mean, mean, SS1[c]*INV_CNT);
    float is   = rsqrtf(var + 1e-5f);
    float scv  = g1[c]*is;
    sc[c] = scv; sh[c] = fmaf(-mean, scv, be1[c]);
  }
  __syncthreads();
  const int lane = threadIdx.x & 63;
  const int wv   = threadIdx.x >> 6;
  const size_t r = (size_t)blockIdx.x*128 + (size_t)(wv>>1)*64 + lane;
  const int h = wv & 1;                       // wave-uniform output half
  const uint4* row = (const uint4*)(x2 + (r<<6));
  float f[64];
#pragma unroll
  for (int q=0;q<8;q++){
    uint4 v = row[q];
    f[q*8+0]=bf2f(v.x&0xffffu); f[q*8+1]=bf2f(v.x>>16);
    f[q*8+2]=bf2f(v.y&0xffffu); f[q*8+3]=bf2f(v.y>>16);
    f[q*8+4]=bf2f(v.z&0xffffu); f[q*8+5]=bf2f(v.z>>16);
    f[q*8+6]=bf2f(v.w&0xffffu); f[q*8+7]=bf2f(v.w>>16);
  }
#pragma unroll
  for (int c=0;c<64;c++) f[c] = fmaxf(fmaf(f[c], sc[c], sh[c]), 0.f);
  float acc[64];
#pragma unroll
  for (int o=0;o<64;o++) acc[o]=b2[h*64+o];
#pragma unroll
  for (int o=0;o<64;o++){
    const float* wr = W2 + (size_t)(h*64+o)*64;
    float a = acc[o];
#pragma unroll
    for (int c=0;c<64;c++) a = fmaf(f[c], wr[c], a);
    acc[o]=a;
  }
  uint4* orow = (uint4*)(x3 + ((r<<7) + (size_t)(h<<6)));
#pragma unroll
  for (int q=0;q<8;q++){
    uint4 v;
    v.x = (uint)f2bf(acc[q*8+0]) | ((uint)f2bf(acc[q*8+1])<<16);
    v.y = (uint)f2bf(acc[q*8+2]) | ((uint)f2bf(acc[q*8+3])<<16);
    v.z = (uint)f2bf(acc[q*8+4]) | ((uint)f2bf(acc[q*8+5])<<16);
    v.w = (uint)f2bf(acc[q*8+6]) | ((uint)f2bf(acc[q*8+7])<<16);
    orow[q]=v;
  }
}

// ---------- BN2+ReLU + maxpool over K ----------
__global__ __launch_bounds__(256) void maxpool_kernel(const ushort* __restrict__ x3,
                                                      const float* __restrict__ S2,
                                                      const float* __restrict__ SS2,
                                                      const float* __restrict__ g2,
                                                      const float* __restrict__ be2,
                                                      float* __restrict__ outp){
  const int lane = threadIdx.x & 63, wv = threadIdx.x >> 6;
  const int bm = blockIdx.x*4 + wv;           // 16384 (b,m) groups
  const int c0 = lane*2, c1 = c0+1;
  float mean0 = S2[c0]*INV_CNT;
  float var0  = fmaf(-mean0, mean0, SS2[c0]*INV_CNT);
  float s0 = g2[c0]*rsqrtf(var0+1e-5f);
  float h0 = fmaf(-mean0, s0, be2[c0]);
  float mean1 = S2[c1]*INV_CNT;
  float var1  = fmaf(-mean1, mean1, SS2[c1]*INV_CNT);
  float s1 = g2[c1]*rsqrtf(var1+1e-5f);
  float h1 = fmaf(-mean1, s1, be2[c1]);
  const uint* rb = (const uint*)(x3 + (size_t)bm*K_SMP*128);
  float mx0 = 0.f, mx1 = 0.f;                 // relu floor
#pragma unroll
  for (int k=0;k<K_SMP;k++){
    uint v = rb[k*64 + lane];
    float a0 = bf2f(v & 0xffffu), a1 = bf2f(v >> 16);
    mx0 = fmaxf(mx0, fmaxf(fmaf(a0, s0, h0), 0.f));
    mx1 = fmaxf(mx1, fmaxf(fmaf(a1, s1, h1), 0.f));
  }
  float2* o2 = (float2*)(outp + (size_t)bm*128);
  o2[lane] = make_float2(mx0, mx1);
}

// ---------- launch ----------
extern "C" void kernel_launch(void* const* d_in, const int* in_sizes, int n_in,
                              void* d_out, int out_size, void* d_ws, size_t ws_size,
                              hipStream_t stream){
  const float* xyz    = (const float*)d_in[0];
  const float* points = (const float*)d_in[1];
  const float* w0  = (const float*)d_in[2];
  const float* b0  = (const float*)d_in[3];
  const float* g0  = (const float*)d_in[4];
  const float* be0 = (const float*)d_in[5];
  const float* w1  = (const float*)d_in[6];
  const float* b1  = (const float*)d_in[7];
  const float* g1  = (const float*)d_in[8];
  const float* be1 = (const float*)d_in[9];
  const float* w2  = (const float*)d_in[10];
  const float* b2  = (const float*)d_in[11];
  const float* g2  = (const float*)d_in[12];
  const float* be2 = (const float*)d_in[13];

  float* out      = (float*)d_out;
  float* newxyz   = out;                       // [16,1024,3]
  float* outp     = out + (size_t)B_SZ*M_PTS*3; // [16,1024,128]

  char* ws = (char*)d_ws;
  // ws layout (needs ~205.6 MB):
  //   [0,2MB)          group_idx  int[16][1024][32]
  //   [2MB, +2KB)      stats: S0,SS0,S1,SS1 (64 each), S2,SS2 (128 each)
  //   [4MB, +134MB)    x1 (bf16, 67MB)  then reused by x3 (bf16, 134MB)
  //   [138.4MB,+67MB)  x2 (bf16)
  int*   gidx  = (int*)ws;
  float* stats = (float*)(ws + (2u<<20));
  float* S0 = stats,      *SS0 = stats+64;
  float* S1 = stats+128,  *SS1 = stats+192;
  float* S2 = stats+256,  *SS2 = stats+384;
  ushort* x1 = (ushort*)(ws + (4u<<20));
  ushort* x3 = (ushort*)(ws + (4u<<20));
  ushort* x2 = (ushort*)(ws + (4u<<20) + 134217728u);

  hipMemsetAsync(stats, 0, 512*sizeof(float), stream);
  fps_kernel  <<<B_SZ, 512, 0, stream>>>(xyz, newxyz);
  ballq_kernel<<<1024, 256, 0, stream>>>(xyz, newxyz, gidx);
  conv0_kernel<<<NROWS/256, 256, 0, stream>>>(xyz, points, newxyz, gidx, w0, b0, x1);
  stats_kernel<64><<<256, 256, 0, stream>>>(x1, S0, SS0);
  conv1_kernel<<<NROWS/256, 256, 0, stream>>>(x1, S0, SS0, g0, be0, w1, b1, x2);
  stats_kernel<64><<<256, 256, 0, stream>>>(x2, S1, SS1);
  conv2_kernel<<<NROWS/128, 256, 0, stream>>>(x2, S1, SS1, g1, be1, w2, b2, x3);
  stats_kernel<128><<<256, 256, 0, stream>>>(x3, S2, SS2);
  maxpool_kernel<<<NROWS/128, 256, 0, stream>>>(x3, S2, SS2, g2, be2, outp);
}

// Round 2
// 2360.188 us; speedup vs baseline: 1.2486x; 1.2486x over previous
//
#include <hip/hip_runtime.h>

typedef unsigned int uint;
typedef unsigned short ushort;
typedef unsigned long long u64;

#define N_PTS 4096
#define B_SZ 16
#define M_PTS 1024
#define K_SMP 32
#define NROWS (B_SZ*M_PTS*K_SMP)   /* 524288 */
#define INV_CNT (1.0f/524288.0f)   /* exact: 2^-19 */

// ---------- helpers ----------
__device__ __forceinline__ float sqdist3(float ax,float ay,float az,float bx,float by,float bz){
  // exact-match of numpy/XLA f32: separate sub/mul/add, no FMA contraction
  float dx=__fsub_rn(ax,bx), dy=__fsub_rn(ay,by), dz=__fsub_rn(az,bz);
  return __fadd_rn(__fadd_rn(__fmul_rn(dx,dx),__fmul_rn(dy,dy)),__fmul_rn(dz,dz));
}
__device__ __forceinline__ ushort f2bf(float x){
  uint u = __float_as_uint(x);
  u = (u + 0x7fffu + ((u>>16)&1u)) >> 16;   // RNE
  return (ushort)u;
}
__device__ __forceinline__ float bf2f(uint u){ return __uint_as_float(u<<16); }

// ---------- FPS: DPP-based all-VALU argmax reduction ----------
// Candidate: u64 key = (dist_bits<<32) | ~idx  (unique -> total order, exact
// lowest-index tie-break), plus the candidate point's coords carried along so
// the next step never does a dependent LDS fetch of the centroid.
struct C5 { uint kl, kh; float x, y, z; };

__device__ __forceinline__ void cmerge(C5& a, const C5& b){
  u64 ka = ((u64)a.kh << 32) | a.kl;
  u64 kb = ((u64)b.kh << 32) | b.kl;
  bool t = kb > ka;
  a.kl = t ? b.kl : a.kl;
  a.kh = t ? b.kh : a.kh;
  a.x  = t ? b.x  : a.x;
  a.y  = t ? b.y  : a.y;
  a.z  = t ? b.z  : a.z;
}

template<int CTRL>
__device__ __forceinline__ uint dppu(uint v){
  return (uint)__builtin_amdgcn_update_dpp((int)v, (int)v, CTRL, 0xf, 0xf, false);
}
template<int CTRL>
__device__ __forceinline__ void dppmerge(C5& a){
  C5 b;
  b.kl = dppu<CTRL>(a.kl);
  b.kh = dppu<CTRL>(a.kh);
  b.x  = __uint_as_float(dppu<CTRL>(__float_as_uint(a.x)));
  b.y  = __uint_as_float(dppu<CTRL>(__float_as_uint(a.y)));
  b.z  = __uint_as_float(dppu<CTRL>(__float_as_uint(a.z)));
  cmerge(a, b);
}

// one block of 256 threads per batch; 16 points per thread in registers
__global__ __launch_bounds__(256) void fps_kernel(const float* __restrict__ xyz,
                                                  float* __restrict__ out_newxyz){
  const int b = blockIdx.x;
  const int t = threadIdx.x;
  __shared__ float sx[N_PTS], sy[N_PTS], sz[N_PTS];
  __shared__ uint xch[2][4][8];
  const float* src = xyz + (size_t)b*N_PTS*3;
  for (int i = t; i < N_PTS*3; i += 256){
    float v = src[i];
    int p = i/3, j = i%3;
    (j==0?sx:(j==1?sy:sz))[p] = v;
  }
  __syncthreads();
  const int p0 = t*16;
  float px[16], py[16], pz[16], dist[16];
  uint nlo[16];
#pragma unroll
  for (int i=0;i<16;i++){
    px[i]=sx[p0+i]; py[i]=sy[p0+i]; pz[i]=sz[p0+i];
    dist[i]=1e10f; nlo[i] = ~(uint)(p0+i);
  }
  float cx = sx[0], cy = sy[0], cz = sz[0];
  const int w = t >> 6, lane = t & 63;
  float* outx = out_newxyz + (size_t)b*M_PTS*3;
  for (int s = 0; s < M_PTS; ++s){
    if (t == 0){ outx[s*3+0]=cx; outx[s*3+1]=cy; outx[s*3+2]=cz; }
    // phase A: per-thread dist update + 4-point group merges (keeps reg pressure low)
    C5 g[4];
#pragma unroll
    for (int q=0;q<4;q++){
      C5 c[4];
#pragma unroll
      for (int j=0;j<4;j++){
        int i = q*4+j;
        float d  = sqdist3(px[i],py[i],pz[i],cx,cy,cz);
        float nd = fminf(dist[i], d);
        dist[i] = nd;
        c[j].kh = __float_as_uint(nd); c[j].kl = nlo[i];
        c[j].x = px[i]; c[j].y = py[i]; c[j].z = pz[i];
      }
      cmerge(c[0], c[1]); cmerge(c[2], c[3]); cmerge(c[0], c[2]);
      g[q] = c[0];
    }
    cmerge(g[0], g[1]); cmerge(g[2], g[3]); cmerge(g[0], g[2]);
    C5 a = g[0];
    // phase B: 64-lane all-VALU butterfly -> lane 63 holds wave winner
    dppmerge<0x111>(a);   // row_shr:1
    dppmerge<0x112>(a);   // row_shr:2
    dppmerge<0x114>(a);   // row_shr:4
    dppmerge<0x118>(a);   // row_shr:8
    dppmerge<0x142>(a);   // row_bcast:15
    dppmerge<0x143>(a);   // row_bcast:31
    // phase C: cross-wave exchange (parity double-buffer, single barrier/step)
    const int par = s & 1;
    if (lane == 63){
      xch[par][w][0]=a.kl; xch[par][w][1]=a.kh;
      xch[par][w][2]=__float_as_uint(a.x);
      xch[par][w][3]=__float_as_uint(a.y);
      xch[par][w][4]=__float_as_uint(a.z);
    }
    __syncthreads();
    C5 r;
    r.kl = xch[par][0][0]; r.kh = xch[par][0][1];
    r.x = __uint_as_float(xch[par][0][2]);
    r.y = __uint_as_float(xch[par][0][3]);
    r.z = __uint_as_float(xch[par][0][4]);
#pragma unroll
    for (int q=1;q<4;q++){
      C5 o;
      o.kl = xch[par][q][0]; o.kh = xch[par][q][1];
      o.x = __uint_as_float(xch[par][q][2]);
      o.y = __uint_as_float(xch[par][q][3]);
      o.z = __uint_as_float(xch[par][q][4]);
      cmerge(r, o);
    }
    cx = r.x; cy = r.y; cz = r.z;
  }
}

// ---------- 2. ball query (exact f32, first-32 in index order) ----------
// 1024 blocks; block = 4 waves handles 16 centroids of one batch
__global__ __launch_bounds__(256) void ballq_kernel(const float* __restrict__ xyz,
                                                    const float* __restrict__ newxyz,
                                                    int* __restrict__ gidx){
  const int blk = blockIdx.x;
  const int b = blk >> 6;
  const int mbase = (blk & 63) * 16;
  __shared__ float sx[N_PTS], sy[N_PTS], sz[N_PTS];
  const float* src = xyz + (size_t)b*N_PTS*3;
  for (int i = threadIdx.x; i < N_PTS*3; i += 256){
    float v = src[i]; int p = i/3, j = i%3;
    (j==0?sx:(j==1?sy:sz))[p] = v;
  }
  __syncthreads();
  const int w = threadIdx.x >> 6, lane = threadIdx.x & 63;
  const float R2 = (float)(0.2*0.2);   // f32(f64 product) — matches reference cast
  for (int mm = w; mm < 16; mm += 4){
    const int m = mbase + mm;
    const float* c = newxyz + ((size_t)b*M_PTS + m)*3;
    float cx = c[0], cy = c[1], cz = c[2];
    int* gout = gidx + ((size_t)b*M_PTS + m)*K_SMP;
    int cnt = 0;
    for (int base = 0; base < N_PTS && cnt < K_SMP; base += 64){
      int p = base + lane;
      float d = sqdist3(sx[p],sy[p],sz[p],cx,cy,cz);
      bool in = (d <= R2);
      unsigned long long mask = __ballot(in);
      int prefix = __popcll(mask & ((1ull << lane) - 1ull));
      int slot = cnt + prefix;
      if (in && slot < K_SMP) gout[slot] = p;
      cnt += __popcll(mask);
    }
    if (cnt < K_SMP){
      int slot = cnt + lane;
      if (slot < K_SMP) gout[slot] = 0;
    }
  }
}

// ---------- 3. conv0: gather + concat + 67->64 matmul (+bias), write bf16 ----------
__global__ __launch_bounds__(256) void conv0_kernel(const float* __restrict__ xyz,
                                                    const float* __restrict__ points,
                                                    const float* __restrict__ newxyz,
                                                    const int* __restrict__ gidx,
                                                    const float* __restrict__ W0,
                                                    const float* __restrict__ b0,
                                                    ushort* __restrict__ x1){
  const int r = blockIdx.x*256 + threadIdx.x;         // 524288 rows
  const int b = r >> 15, m = (r >> 5) & 1023;
  const int g = gidx[r];
  const float* pc = newxyz + ((size_t)(b<<10) + m)*3;
  const float* pp = xyz    + ((size_t)(b<<12) + g)*3;
  float f[67];
  f[0]=pp[0]-pc[0]; f[1]=pp[1]-pc[1]; f[2]=pp[2]-pc[2];
  const float4* prow = (const float4*)(points + (((size_t)(b<<12) + g) << 6));
#pragma unroll
  for (int q=0;q<16;q++){
    float4 v = prow[q];
    f[3+4*q]=v.x; f[4+4*q]=v.y; f[5+4*q]=v.z; f[6+4*q]=v.w;
  }
  float acc[64];
#pragma unroll
  for (int o=0;o<64;o++) acc[o]=b0[o];
#pragma unroll
  for (int o=0;o<64;o++){
    const float* wr = W0 + o*67;
    float a = acc[o];
#pragma unroll
    for (int c=0;c<67;c++) a = fmaf(f[c], wr[c], a);
    acc[o]=a;
  }
  uint4* orow = (uint4*)(x1 + ((size_t)r << 6));
#pragma unroll
  for (int q=0;q<8;q++){
    uint4 v;
    v.x = (uint)f2bf(acc[q*8+0]) | ((uint)f2bf(acc[q*8+1])<<16);
    v.y = (uint)f2bf(acc[q*8+2]) | ((uint)f2bf(acc[q*8+3])<<16);
    v.z = (uint)f2bf(acc[q*8+4]) | ((uint)f2bf(acc[q*8+5])<<16);
    v.w = (uint)f2bf(acc[q*8+6]) | ((uint)f2bf(acc[q*8+7])<<16);
    orow[q]=v;
  }
}

// ---------- stats: per-channel sum & sumsq over all rows ----------
template<int C>
__global__ __launch_bounds__(256) void stats_kernel(const ushort* __restrict__ x,
                                                    float* __restrict__ S,
                                                    float* __restrict__ SS){
  constexpr int RL = 256 / C;
  const int c  = threadIdx.x % C;
  const int rl = threadIdx.x / C;
  const int rows_per_block = NROWS / 256;   // gridDim = 256
  const int r0 = blockIdx.x * rows_per_block;
  const int r1 = r0 + rows_per_block;
  float s = 0.f, ss = 0.f;
  for (int r = r0 + rl; r < r1; r += RL){
    float v = bf2f((uint)x[(size_t)r*C + c]);
    s += v; ss = fmaf(v, v, ss);
  }
  __shared__ float ls[256], lss[256];
  ls[threadIdx.x] = s; lss[threadIdx.x] = ss;
  __syncthreads();
  if (threadIdx.x < C){
    float a = 0.f, q2 = 0.f;
#pragma unroll
    for (int q = 0; q < RL; q++){ a += ls[q*C + c]; q2 += lss[q*C + c]; }
    atomicAdd(&S[c], a); atomicAdd(&SS[c], q2);
  }
}

// ---------- conv1: BN0+ReLU fused on read, 64->64 ----------
__global__ __launch_bounds__(256) void conv1_kernel(const ushort* __restrict__ x1,
                                                    const float* __restrict__ S0,
                                                    const float* __restrict__ SS0,
                                                    const float* __restrict__ g0,
                                                    const float* __restrict__ be0,
                                                    const float* __restrict__ W1,
                                                    const float* __restrict__ b1,
                                                    ushort* __restrict__ x2){
  __shared__ float sc[64], sh[64];
  if (threadIdx.x < 64){
    int c = threadIdx.x;
    float mean = S0[c]*INV_CNT;
    float var  = fmaf(-mean, mean, SS0[c]*INV_CNT);
    float is   = rsqrtf(var + 1e-5f);
    float scv  = g0[c]*is;
    sc[c] = scv; sh[c] = fmaf(-mean, scv, be0[c]);
  }
  __syncthreads();
  const size_t r = (size_t)blockIdx.x*256 + threadIdx.x;
  const uint4* row = (const uint4*)(x1 + (r<<6));
  float f[64];
#pragma unroll
  for (int q=0;q<8;q++){
    uint4 v = row[q];
    f[q*8+0]=bf2f(v.x&0xffffu); f[q*8+1]=bf2f(v.x>>16);
    f[q*8+2]=bf2f(v.y&0xffffu); f[q*8+3]=bf2f(v.y>>16);
    f[q*8+4]=bf2f(v.z&0xffffu); f[q*8+5]=bf2f(v.z>>16);
    f[q*8+6]=bf2f(v.w&0xffffu); f[q*8+7]=bf2f(v.w>>16);
  }
#pragma unroll
  for (int c=0;c<64;c++) f[c] = fmaxf(fmaf(f[c], sc[c], sh[c]), 0.f);
  float acc[64];
#pragma unroll
  for (int o=0;o<64;o++) acc[o]=b1[o];
#pragma unroll
  for (int o=0;o<64;o++){
    const float* wr = W1 + o*64;
    float a = acc[o];
#pragma unroll
    for (int c=0;c<64;c++) a = fmaf(f[c], wr[c], a);
    acc[o]=a;
  }
  uint4* orow = (uint4*)(x2 + (r<<6));
#pragma unroll
  for (int q=0;q<8;q++){
    uint4 v;
    v.x = (uint)f2bf(acc[q*8+0]) | ((uint)f2bf(acc[q*8+1])<<16);
    v.y = (uint)f2bf(acc[q*8+2]) | ((uint)f2bf(acc[q*8+3])<<16);
    v.z = (uint)f2bf(acc[q*8+4]) | ((uint)f2bf(acc[q*8+5])<<16);
    v.w = (uint)f2bf(acc[q*8+6]) | ((uint)f2bf(acc[q*8+7])<<16);
    orow[q]=v;
  }
}

// ---------- conv2: BN1+ReLU fused on read, 64->128 (2 waves share a row set) ----------
__global__ __launch_bounds__(256) void conv2_kernel(const ushort* __restrict__ x2,
                                                    const float* __restrict__ S1,
                                                    const float* __restrict__ SS1,
                                                    const float* __restrict__ g1,
                                                    const float* __restrict__ be1,
                                                    const float* __restrict__ W2,
                                                    const float* __restrict__ b2,
                                                    ushort* __restrict__ x3){
  __shared__ float sc[64], sh[64];
  if (threadIdx.x < 64){
    int c = threadIdx.x;
    float mean = S1[c]*INV_CNT;
    float var  = fmaf(-mean, mean, SS1[c]*INV_CNT);
    float is   = rsqrtf(var + 1e-5f);
    float scv  = g1[c]*is;
    sc[c] = scv; sh[c] = fmaf(-mean, scv, be1[c]);
  }
  __syncthreads();
  const int lane = threadIdx.x & 63;
  const int wv   = threadIdx.x >> 6;
  const size_t r = (size_t)blockIdx.x*128 + (size_t)(wv>>1)*64 + lane;
  const int h = wv & 1;                       // wave-uniform output half
  const uint4* row = (const uint4*)(x2 + (r<<6));
  float f[64];
#pragma unroll
  for (int q=0;q<8;q++){
    uint4 v = row[q];
    f[q*8+0]=bf2f(v.x&0xffffu); f[q*8+1]=bf2f(v.x>>16);
    f[q*8+2]=bf2f(v.y&0xffffu); f[q*8+3]=bf2f(v.y>>16);
    f[q*8+4]=bf2f(v.z&0xffffu); f[q*8+5]=bf2f(v.z>>16);
    f[q*8+6]=bf2f(v.w&0xffffu); f[q*8+7]=bf2f(v.w>>16);
  }
#pragma unroll
  for (int c=0;c<64;c++) f[c] = fmaxf(fmaf(f[c], sc[c], sh[c]), 0.f);
  float acc[64];
#pragma unroll
  for (int o=0;o<64;o++) acc[o]=b2[h*64+o];
#pragma unroll
  for (int o=0;o<64;o++){
    const float* wr = W2 + (size_t)(h*64+o)*64;
    float a = acc[o];
#pragma unroll
    for (int c=0;c<64;c++) a = fmaf(f[c], wr[c], a);
    acc[o]=a;
  }
  uint4* orow = (uint4*)(x3 + ((r<<7) + (size_t)(h<<6)));
#pragma unroll
  for (int q=0;q<8;q++){
    uint4 v;
    v.x = (uint)f2bf(acc[q*8+0]) | ((uint)f2bf(acc[q*8+1])<<16);
    v.y = (uint)f2bf(acc[q*8+2]) | ((uint)f2bf(acc[q*8+3])<<16);
    v.z = (uint)f2bf(acc[q*8+4]) | ((uint)f2bf(acc[q*8+5])<<16);
    v.w = (uint)f2bf(acc[q*8+6]) | ((uint)f2bf(acc[q*8+7])<<16);
    orow[q]=v;
  }
}

// ---------- BN2+ReLU + maxpool over K ----------
__global__ __launch_bounds__(256) void maxpool_kernel(const ushort* __restrict__ x3,
                                                      const float* __restrict__ S2,
                                                      const float* __restrict__ SS2,
                                                      const float* __restrict__ g2,
                                                      const float* __restrict__ be2,
                                                      float* __restrict__ outp){
  const int lane = threadIdx.x & 63, wv = threadIdx.x >> 6;
  const int bm = blockIdx.x*4 + wv;           // 16384 (b,m) groups
  const int c0 = lane*2, c1 = c0+1;
  float mean0 = S2[c0]*INV_CNT;
  float var0  = fmaf(-mean0, mean0, SS2[c0]*INV_CNT);
  float s0 = g2[c0]*rsqrtf(var0+1e-5f);
  float h0 = fmaf(-mean0, s0, be2[c0]);
  float mean1 = S2[c1]*INV_CNT;
  float var1  = fmaf(-mean1, mean1, SS2[c1]*INV_CNT);
  float s1 = g2[c1]*rsqrtf(var1+1e-5f);
  float h1 = fmaf(-mean1, s1, be2[c1]);
  const uint* rb = (const uint*)(x3 + (size_t)bm*K_SMP*128);
  float mx0 = 0.f, mx1 = 0.f;                 // relu floor
#pragma unroll
  for (int k=0;k<K_SMP;k++){
    uint v = rb[k*64 + lane];
    float a0 = bf2f(v & 0xffffu), a1 = bf2f(v >> 16);
    mx0 = fmaxf(mx0, fmaxf(fmaf(a0, s0, h0), 0.f));
    mx1 = fmaxf(mx1, fmaxf(fmaf(a1, s1, h1), 0.f));
  }
  float2* o2 = (float2*)(outp + (size_t)bm*128);
  o2[lane] = make_float2(mx0, mx1);
}

// ---------- launch ----------
extern "C" void kernel_launch(void* const* d_in, const int* in_sizes, int n_in,
                              void* d_out, int out_size, void* d_ws, size_t ws_size,
                              hipStream_t stream){
  const float* xyz    = (const float*)d_in[0];
  const float* points = (const float*)d_in[1];
  const float* w0  = (const float*)d_in[2];
  const float* b0  = (const float*)d_in[3];
  const float* g0  = (const float*)d_in[4];
  const float* be0 = (const float*)d_in[5];
  const float* w1  = (const float*)d_in[6];
  const float* b1  = (const float*)d_in[7];
  const float* g1  = (const float*)d_in[8];
  const float* be1 = (const float*)d_in[9];
  const float* w2  = (const float*)d_in[10];
  const float* b2  = (const float*)d_in[11];
  const float* g2  = (const float*)d_in[12];
  const float* be2 = (const float*)d_in[13];

  float* out      = (float*)d_out;
  float* newxyz   = out;                       // [16,1024,3]
  float* outp     = out + (size_t)B_SZ*M_PTS*3; // [16,1024,128]

  char* ws = (char*)d_ws;
  // ws layout (needs ~205.6 MB):
  //   [0,2MB)          group_idx  int[16][1024][32]
  //   [2MB, +2KB)      stats: S0,SS0,S1,SS1 (64 each), S2,SS2 (128 each)
  //   [4MB, +134MB)    x1 (bf16, 67MB)  then reused by x3 (bf16, 134MB)
  //   [138.4MB,+67MB)  x2 (bf16)
  int*   gidx  = (int*)ws;
  float* stats = (float*)(ws + (2u<<20));
  float* S0 = stats,      *SS0 = stats+64;
  float* S1 = stats+128,  *SS1 = stats+192;
  float* S2 = stats+256,  *SS2 = stats+384;
  ushort* x1 = (ushort*)(ws + (4u<<20));
  ushort* x3 = (ushort*)(ws + (4u<<20));
  ushort* x2 = (ushort*)(ws + (4u<<20) + 134217728u);

  hipMemsetAsync(stats, 0, 512*sizeof(float), stream);
  fps_kernel  <<<B_SZ, 256, 0, stream>>>(xyz, newxyz);
  ballq_kernel<<<1024, 256, 0, stream>>>(xyz, newxyz, gidx);
  conv0_kernel<<<NROWS/256, 256, 0, stream>>>(xyz, points, newxyz, gidx, w0, b0, x1);
  stats_kernel<64><<<256, 256, 0, stream>>>(x1, S0, SS0);
  conv1_kernel<<<NROWS/256, 256, 0, stream>>>(x1, S0, SS0, g0, be0, w1, b1, x2);
  stats_kernel<64><<<256, 256, 0, stream>>>(x2, S1, SS1);
  conv2_kernel<<<NROWS/128, 256, 0, stream>>>(x2, S1, SS1, g1, be1, w2, b2, x3);
  stats_kernel<128><<<256, 256, 0, stream>>>(x3, S2, SS2);
  maxpool_kernel<<<NROWS/128, 256, 0, stream>>>(x3, S2, SS2, g2, be2, outp);
}

// Round 3
// 2317.944 us; speedup vs baseline: 1.2713x; 1.0182x over previous
//
#include <hip/hip_runtime.h>

typedef unsigned int uint;
typedef unsigned short ushort;
typedef unsigned long long u64;

#define N_PTS 4096
#define B_SZ 16
#define M_PTS 1024
#define K_SMP 32
#define NROWS (B_SZ*M_PTS*K_SMP)   /* 524288 */
#define INV_CNT (1.0f/524288.0f)   /* exact: 2^-19 */

// ---------- helpers ----------
__device__ __forceinline__ float sqdist3(float ax,float ay,float az,float bx,float by,float bz){
  // exact-match of numpy/XLA f32: separate sub/mul/add, no FMA contraction
  float dx=__fsub_rn(ax,bx), dy=__fsub_rn(ay,by), dz=__fsub_rn(az,bz);
  return __fadd_rn(__fadd_rn(__fmul_rn(dx,dx),__fmul_rn(dy,dy)),__fmul_rn(dz,dz));
}
__device__ __forceinline__ ushort f2bf(float x){
  uint u = __float_as_uint(x);
  u = (u + 0x7fffu + ((u>>16)&1u)) >> 16;   // RNE
  return (ushort)u;
}
__device__ __forceinline__ float bf2f(uint u){ return __uint_as_float(u<<16); }

// ---------- FPS: key-only DPP argmax ----------
// key = (dist_bits<<32) | ~idx : unique, max == (largest dist, lowest idx)
__device__ __forceinline__ void kmerge(uint& kl, uint& kh, uint okl, uint okh){
  u64 a = ((u64)kh << 32) | kl;
  u64 b = ((u64)okh << 32) | okl;
  bool t = b > a;
  kl = t ? okl : kl;
  kh = t ? okh : kh;
}
template<int CTRL>
__device__ __forceinline__ uint dppu(uint v){
  return (uint)__builtin_amdgcn_update_dpp((int)v, (int)v, CTRL, 0xf, 0xf, false);
}
template<int CTRL>
__device__ __forceinline__ void dppkmerge(uint& kl, uint& kh){
  uint okl = dppu<CTRL>(kl);
  uint okh = dppu<CTRL>(kh);
  kmerge(kl, kh, okl, okh);
}

// one block of 1024 threads per batch; 4 points/thread in registers
__global__ __launch_bounds__(1024, 4) void fps_kernel(const float* __restrict__ xyz,
                                                      float* __restrict__ out_newxyz){
  const int b = blockIdx.x;
  const int t = threadIdx.x;
  __shared__ float4 sxyz[N_PTS];          // 64 KB, coords for final winner fetch
  __shared__ uint   xch[2][16][2];        // per-wave winner keys, parity dbuf
  const float* src = xyz + (size_t)b*N_PTS*3;
  for (int i = t; i < N_PTS*3; i += 1024){
    float v = src[i];
    int p = i/3, j = i%3;
    ((float*)&sxyz[p])[j] = v;
  }
  __syncthreads();
  const int p0 = t*4;
  float px[4], py[4], pz[4], dist[4];
  uint nl[4];
#pragma unroll
  for (int i=0;i<4;i++){
    float4 c = sxyz[p0+i];
    px[i]=c.x; py[i]=c.y; pz[i]=c.z;
    dist[i]=1e10f; nl[i] = ~(uint)(p0+i);
  }
  float4 c0 = sxyz[0];
  float cx = c0.x, cy = c0.y, cz = c0.z;
  const int w = t >> 6, lane = t & 63;
  float* outx = out_newxyz + (size_t)b*M_PTS*3;
  for (int s = 0; s < M_PTS; ++s){
    if (t == 0){ outx[s*3+0]=cx; outx[s*3+1]=cy; outx[s*3+2]=cz; }
    // A: per-thread dist update + 4-way local tree (key-only)
    uint khv[4];
#pragma unroll
    for (int i=0;i<4;i++){
      float d  = sqdist3(px[i],py[i],pz[i],cx,cy,cz);
      float nd = fminf(dist[i], d);
      dist[i] = nd;
      khv[i] = __float_as_uint(nd);
    }
    uint al=nl[0], ah=khv[0];
    kmerge(al, ah, nl[1], khv[1]);
    uint bl=nl[2], bh=khv[2];
    kmerge(bl, bh, nl[3], khv[3]);
    kmerge(al, ah, bl, bh);
    // B: 64-lane all-VALU butterfly, key only -> lane 63 = wave winner
    dppkmerge<0x111>(al, ah);   // row_shr:1
    dppkmerge<0x112>(al, ah);   // row_shr:2
    dppkmerge<0x114>(al, ah);   // row_shr:4
    dppkmerge<0x118>(al, ah);   // row_shr:8
    dppkmerge<0x142>(al, ah);   // row_bcast:15
    dppkmerge<0x143>(al, ah);   // row_bcast:31
    // C: cross-wave merge, lane-parallel (every wave redundantly)
    const int par = s & 1;
    if (lane == 63){ xch[par][w][0] = al; xch[par][w][1] = ah; }
    __syncthreads();
    uint ckl = xch[par][lane & 15][0];
    uint ckh = xch[par][lane & 15][1];
    dppkmerge<0x111>(ckl, ckh);
    dppkmerge<0x112>(ckl, ckh);
    dppkmerge<0x114>(ckl, ckh);
    dppkmerge<0x118>(ckl, ckh);   // lane 15 (each row) = global winner
    uint wkl = (uint)__builtin_amdgcn_readlane((int)ckl, 15);
    uint idx = ~wkl;
    float4 cc = sxyz[idx];        // uniform broadcast read
    cx = cc.x; cy = cc.y; cz = cc.z;
  }
}

// ---------- 2. ball query (exact f32, first-32 in index order) ----------
// 1024 blocks; block = 4 waves handles 16 centroids of one batch
__global__ __launch_bounds__(256) void ballq_kernel(const float* __restrict__ xyz,
                                                    const float* __restrict__ newxyz,
                                                    int* __restrict__ gidx){
  const int blk = blockIdx.x;
  const int b = blk >> 6;
  const int mbase = (blk & 63) * 16;
  __shared__ float sx[N_PTS], sy[N_PTS], sz[N_PTS];
  const float* src = xyz + (size_t)b*N_PTS*3;
  for (int i = threadIdx.x; i < N_PTS*3; i += 256){
    float v = src[i]; int p = i/3, j = i%3;
    (j==0?sx:(j==1?sy:sz))[p] = v;
  }
  __syncthreads();
  const int w = threadIdx.x >> 6, lane = threadIdx.x & 63;
  const float R2 = (float)(0.2*0.2);   // f32(f64 product) — matches reference cast
  for (int mm = w; mm < 16; mm += 4){
    const int m = mbase + mm;
    const float* c = newxyz + ((size_t)b*M_PTS + m)*3;
    float cx = c[0], cy = c[1], cz = c[2];
    int* gout = gidx + ((size_t)b*M_PTS + m)*K_SMP;
    int cnt = 0;
    for (int base = 0; base < N_PTS && cnt < K_SMP; base += 64){
      int p = base + lane;
      float d = sqdist3(sx[p],sy[p],sz[p],cx,cy,cz);
      bool in = (d <= R2);
      unsigned long long mask = __ballot(in);
      int prefix = __popcll(mask & ((1ull << lane) - 1ull));
      int slot = cnt + prefix;
      if (in && slot < K_SMP) gout[slot] = p;
      cnt += __popcll(mask);
    }
    if (cnt < K_SMP){
      int slot = cnt + lane;
      if (slot < K_SMP) gout[slot] = 0;
    }
  }
}

// ---------- 3. conv0: gather + concat + 67->64 matmul (+bias), write bf16 ----------
__global__ __launch_bounds__(256) void conv0_kernel(const float* __restrict__ xyz,
                                                    const float* __restrict__ points,
                                                    const float* __restrict__ newxyz,
                                                    const int* __restrict__ gidx,
                                                    const float* __restrict__ W0,
                                                    const float* __restrict__ b0,
                                                    ushort* __restrict__ x1){
  const int r = blockIdx.x*256 + threadIdx.x;         // 524288 rows
  const int b = r >> 15, m = (r >> 5) & 1023;
  const int g = gidx[r];
  const float* pc = newxyz + ((size_t)(b<<10) + m)*3;
  const float* pp = xyz    + ((size_t)(b<<12) + g)*3;
  float f[67];
  f[0]=pp[0]-pc[0]; f[1]=pp[1]-pc[1]; f[2]=pp[2]-pc[2];
  const float4* prow = (const float4*)(points + (((size_t)(b<<12) + g) << 6));
#pragma unroll
  for (int q=0;q<16;q++){
    float4 v = prow[q];
    f[3+4*q]=v.x; f[4+4*q]=v.y; f[5+4*q]=v.z; f[6+4*q]=v.w;
  }
  float acc[64];
#pragma unroll
  for (int o=0;o<64;o++) acc[o]=b0[o];
#pragma unroll
  for (int o=0;o<64;o++){
    const float* wr = W0 + o*67;
    float a = acc[o];
#pragma unroll
    for (int c=0;c<67;c++) a = fmaf(f[c], wr[c], a);
    acc[o]=a;
  }
  uint4* orow = (uint4*)(x1 + ((size_t)r << 6));
#pragma unroll
  for (int q=0;q<8;q++){
    uint4 v;
    v.x = (uint)f2bf(acc[q*8+0]) | ((uint)f2bf(acc[q*8+1])<<16);
    v.y = (uint)f2bf(acc[q*8+2]) | ((uint)f2bf(acc[q*8+3])<<16);
    v.z = (uint)f2bf(acc[q*8+4]) | ((uint)f2bf(acc[q*8+5])<<16);
    v.w = (uint)f2bf(acc[q*8+6]) | ((uint)f2bf(acc[q*8+7])<<16);
    orow[q]=v;
  }
}

// ---------- stats: per-channel sum & sumsq over all rows ----------
template<int C>
__global__ __launch_bounds__(256) void stats_kernel(const ushort* __restrict__ x,
                                                    float* __restrict__ S,
                                                    float* __restrict__ SS){
  constexpr int RL = 256 / C;
  const int c  = threadIdx.x % C;
  const int rl = threadIdx.x / C;
  const int rows_per_block = NROWS / 256;   // gridDim = 256
  const int r0 = blockIdx.x * rows_per_block;
  const int r1 = r0 + rows_per_block;
  float s = 0.f, ss = 0.f;
  for (int r = r0 + rl; r < r1; r += RL){
    float v = bf2f((uint)x[(size_t)r*C + c]);
    s += v; ss = fmaf(v, v, ss);
  }
  __shared__ float ls[256], lss[256];
  ls[threadIdx.x] = s; lss[threadIdx.x] = ss;
  __syncthreads();
  if (threadIdx.x < C){
    float a = 0.f, q2 = 0.f;
#pragma unroll
    for (int q = 0; q < RL; q++){ a += ls[q*C + c]; q2 += lss[q*C + c]; }
    atomicAdd(&S[c], a); atomicAdd(&SS[c], q2);
  }
}

// ---------- conv1: BN0+ReLU fused on read, 64->64 ----------
__global__ __launch_bounds__(256) void conv1_kernel(const ushort* __restrict__ x1,
                                                    const float* __restrict__ S0,
                                                    const float* __restrict__ SS0,
                                                    const float* __restrict__ g0,
                                                    const float* __restrict__ be0,
                                                    const float* __restrict__ W1,
                                                    const float* __restrict__ b1,
                                                    ushort* __restrict__ x2){
  __shared__ float sc[64], sh[64];
  if (threadIdx.x < 64){
    int c = threadIdx.x;
    float mean = S0[c]*INV_CNT;
    float var  = fmaf(-mean, mean, SS0[c]*INV_CNT);
    float is   = rsqrtf(var + 1e-5f);
    float scv  = g0[c]*is;
    sc[c] = scv; sh[c] = fmaf(-mean, scv, be0[c]);
  }
  __syncthreads();
  const size_t r = (size_t)blockIdx.x*256 + threadIdx.x;
  const uint4* row = (const uint4*)(x1 + (r<<6));
  float f[64];
#pragma unroll
  for (int q=0;q<8;q++){
    uint4 v = row[q];
    f[q*8+0]=bf2f(v.x&0xffffu); f[q*8+1]=bf2f(v.x>>16);
    f[q*8+2]=bf2f(v.y&0xffffu); f[q*8+3]=bf2f(v.y>>16);
    f[q*8+4]=bf2f(v.z&0xffffu); f[q*8+5]=bf2f(v.z>>16);
    f[q*8+6]=bf2f(v.w&0xffffu); f[q*8+7]=bf2f(v.w>>16);
  }
#pragma unroll
  for (int c=0;c<64;c++) f[c] = fmaxf(fmaf(f[c], sc[c], sh[c]), 0.f);
  float acc[64];
#pragma unroll
  for (int o=0;o<64;o++) acc[o]=b1[o];
#pragma unroll
  for (int o=0;o<64;o++){
    const float* wr = W1 + o*64;
    float a = acc[o];
#pragma unroll
    for (int c=0;c<64;c++) a = fmaf(f[c], wr[c], a);
    acc[o]=a;
  }
  uint4* orow = (uint4*)(x2 + (r<<6));
#pragma unroll
  for (int q=0;q<8;q++){
    uint4 v;
    v.x = (uint)f2bf(acc[q*8+0]) | ((uint)f2bf(acc[q*8+1])<<16);
    v.y = (uint)f2bf(acc[q*8+2]) | ((uint)f2bf(acc[q*8+3])<<16);
    v.z = (uint)f2bf(acc[q*8+4]) | ((uint)f2bf(acc[q*8+5])<<16);
    v.w = (uint)f2bf(acc[q*8+6]) | ((uint)f2bf(acc[q*8+7])<<16);
    orow[q]=v;
  }
}

// ---------- conv2: BN1+ReLU fused on read, 64->128 (2 waves share a row set) ----------
__global__ __launch_bounds__(256) void conv2_kernel(const ushort* __restrict__ x2,
                                                    const float* __restrict__ S1,
                                                    const float* __restrict__ SS1,
                                                    const float* __restrict__ g1,
                                                    const float* __restrict__ be1,
                                                    const float* __restrict__ W2,
                                                    const float* __restrict__ b2,
                                                    ushort* __restrict__ x3){
  __shared__ float sc[64], sh[64];
  if (threadIdx.x < 64){
    int c = threadIdx.x;
    float mean = S1[c]*INV_CNT;
    float var  = fmaf(-mean, mean, SS1[c]*INV_CNT);
    float is   = rsqrtf(var + 1e-5f);
    float scv  = g1[c]*is;
    sc[c] = scv; sh[c] = fmaf(-mean, scv, be1[c]);
  }
  __syncthreads();
  const int lane = threadIdx.x & 63;
  const int wv   = threadIdx.x >> 6;
  const size_t r = (size_t)blockIdx.x*128 + (size_t)(wv>>1)*64 + lane;
  const int h = wv & 1;                       // wave-uniform output half
  const uint4* row = (const uint4*)(x2 + (r<<6));
  float f[64];
#pragma unroll
  for (int q=0;q<8;q++){
    uint4 v = row[q];
    f[q*8+0]=bf2f(v.x&0xffffu); f[q*8+1]=bf2f(v.x>>16);
    f[q*8+2]=bf2f(v.y&0xffffu); f[q*8+3]=bf2f(v.y>>16);
    f[q*8+4]=bf2f(v.z&0xffffu); f[q*8+5]=bf2f(v.z>>16);
    f[q*8+6]=bf2f(v.w&0xffffu); f[q*8+7]=bf2f(v.w>>16);
  }
#pragma unroll
  for (int c=0;c<64;c++) f[c] = fmaxf(fmaf(f[c], sc[c], sh[c]), 0.f);
  float acc[64];
#pragma unroll
  for (int o=0;o<64;o++) acc[o]=b2[h*64+o];
#pragma unroll
  for (int o=0;o<64;o++){
    const float* wr = W2 + (size_t)(h*64+o)*64;
    float a = acc[o];
#pragma unroll
    for (int c=0;c<64;c++) a = fmaf(f[c], wr[c], a);
    acc[o]=a;
  }
  uint4* orow = (uint4*)(x3 + ((r<<7) + (size_t)(h<<6)));
#pragma unroll
  for (int q=0;q<8;q++){
    uint4 v;
    v.x = (uint)f2bf(acc[q*8+0]) | ((uint)f2bf(acc[q*8+1])<<16);
    v.y = (uint)f2bf(acc[q*8+2]) | ((uint)f2bf(acc[q*8+3])<<16);
    v.z = (uint)f2bf(acc[q*8+4]) | ((uint)f2bf(acc[q*8+5])<<16);
    v.w = (uint)f2bf(acc[q*8+6]) | ((uint)f2bf(acc[q*8+7])<<16);
    orow[q]=v;
  }
}

// ---------- BN2+ReLU + maxpool over K ----------
__global__ __launch_bounds__(256) void maxpool_kernel(const ushort* __restrict__ x3,
                                                      const float* __restrict__ S2,
                                                      const float* __restrict__ SS2,
                                                      const float* __restrict__ g2,
                                                      const float* __restrict__ be2,
                                                      float* __restrict__ outp){
  const int lane = threadIdx.x & 63, wv = threadIdx.x >> 6;
  const int bm = blockIdx.x*4 + wv;           // 16384 (b,m) groups
  const int c0 = lane*2, c1 = c0+1;
  float mean0 = S2[c0]*INV_CNT;
  float var0  = fmaf(-mean0, mean0, SS2[c0]*INV_CNT);
  float s0 = g2[c0]*rsqrtf(var0+1e-5f);
  float h0 = fmaf(-mean0, s0, be2[c0]);
  float mean1 = S2[c1]*INV_CNT;
  float var1  = fmaf(-mean1, mean1, SS2[c1]*INV_CNT);
  float s1 = g2[c1]*rsqrtf(var1+1e-5f);
  float h1 = fmaf(-mean1, s1, be2[c1]);
  const uint* rb = (const uint*)(x3 + (size_t)bm*K_SMP*128);
  float mx0 = 0.f, mx1 = 0.f;                 // relu floor
#pragma unroll
  for (int k=0;k<K_SMP;k++){
    uint v = rb[k*64 + lane];
    float a0 = bf2f(v & 0xffffu), a1 = bf2f(v >> 16);
    mx0 = fmaxf(mx0, fmaxf(fmaf(a0, s0, h0), 0.f));
    mx1 = fmaxf(mx1, fmaxf(fmaf(a1, s1, h1), 0.f));
  }
  float2* o2 = (float2*)(outp + (size_t)bm*128);
  o2[lane] = make_float2(mx0, mx1);
}

// ---------- launch ----------
extern "C" void kernel_launch(void* const* d_in, const int* in_sizes, int n_in,
                              void* d_out, int out_size, void* d_ws, size_t ws_size,
                              hipStream_t stream){
  const float* xyz    = (const float*)d_in[0];
  const float* points = (const float*)d_in[1];
  const float* w0  = (const float*)d_in[2];
  const float* b0  = (const float*)d_in[3];
  const float* g0  = (const float*)d_in[4];
  const float* be0 = (const float*)d_in[5];
  const float* w1  = (const float*)d_in[6];
  const float* b1  = (const float*)d_in[7];
  const float* g1  = (const float*)d_in[8];
  const float* be1 = (const float*)d_in[9];
  const float* w2  = (const float*)d_in[10];
  const float* b2  = (const float*)d_in[11];
  const float* g2  = (const float*)d_in[12];
  const float* be2 = (const float*)d_in[13];

  float* out      = (float*)d_out;
  float* newxyz   = out;                       // [16,1024,3]
  float* outp     = out + (size_t)B_SZ*M_PTS*3; // [16,1024,128]

  char* ws = (char*)d_ws;
  // ws layout (needs ~205.6 MB):
  //   [0,2MB)          group_idx  int[16][1024][32]
  //   [2MB, +2KB)      stats: S0,SS0,S1,SS1 (64 each), S2,SS2 (128 each)
  //   [4MB, +134MB)    x1 (bf16, 67MB)  then reused by x3 (bf16, 134MB)
  //   [138.4MB,+67MB)  x2 (bf16)
  int*   gidx  = (int*)ws;
  float* stats = (float*)(ws + (2u<<20));
  float* S0 = stats,      *SS0 = stats+64;
  float* S1 = stats+128,  *SS1 = stats+192;
  float* S2 = stats+256,  *SS2 = stats+384;
  ushort* x1 = (ushort*)(ws + (4u<<20));
  ushort* x3 = (ushort*)(ws + (4u<<20));
  ushort* x2 = (ushort*)(ws + (4u<<20) + 134217728u);

  hipMemsetAsync(stats, 0, 512*sizeof(float), stream);
  fps_kernel  <<<B_SZ, 1024, 0, stream>>>(xyz, newxyz);
  ballq_kernel<<<1024, 256, 0, stream>>>(xyz, newxyz, gidx);
  conv0_kernel<<<NROWS/256, 256, 0, stream>>>(xyz, points, newxyz, gidx, w0, b0, x1);
  stats_kernel<64><<<256, 256, 0, stream>>>(x1, S0, SS0);
  conv1_kernel<<<NROWS/256, 256, 0, stream>>>(x1, S0, SS0, g0, be0, w1, b1, x2);
  stats_kernel<64><<<256, 256, 0, stream>>>(x2, S1, SS1);
  conv2_kernel<<<NROWS/128, 256, 0, stream>>>(x2, S1, SS1, g1, be1, w2, b2, x3);
  stats_kernel<128><<<256, 256, 0, stream>>>(x3, S2, SS2);
  maxpool_kernel<<<NROWS/128, 256, 0, stream>>>(x3, S2, SS2, g2, be2, outp);
}

// Round 4
// 2164.583 us; speedup vs baseline: 1.3614x; 1.0708x over previous
//
#include <hip/hip_runtime.h>

typedef unsigned int uint;
typedef unsigned short ushort;
typedef unsigned long long u64;

#define N_PTS 4096
#define B_SZ 16
#define M_PTS 1024
#define K_SMP 32
#define NROWS (B_SZ*M_PTS*K_SMP)   /* 524288 */
#define INV_CNT (1.0f/524288.0f)   /* exact: 2^-19 */

// ---------- helpers ----------
__device__ __forceinline__ float sqdist3(float ax,float ay,float az,float bx,float by,float bz){
  // exact-match of numpy/XLA f32: separate sub/mul/add, no FMA contraction
  float dx=__fsub_rn(ax,bx), dy=__fsub_rn(ay,by), dz=__fsub_rn(az,bz);
  return __fadd_rn(__fadd_rn(__fmul_rn(dx,dx),__fmul_rn(dy,dy)),__fmul_rn(dz,dz));
}
__device__ __forceinline__ ushort f2bf(float x){
  uint u = __float_as_uint(x);
  u = (u + 0x7fffu + ((u>>16)&1u)) >> 16;   // RNE
  return (ushort)u;
}
__device__ __forceinline__ float bf2f(uint u){ return __uint_as_float(u<<16); }

// ---------- FPS: key-only DPP argmax ----------
// key = (dist_bits<<32) | ~idx : unique, max == (largest dist, lowest idx)
__device__ __forceinline__ void kmerge(uint& kl, uint& kh, uint okl, uint okh){
  u64 a = ((u64)kh << 32) | kl;
  u64 b = ((u64)okh << 32) | okl;
  bool t = b > a;
  kl = t ? okl : kl;
  kh = t ? okh : kh;
}
template<int CTRL>
__device__ __forceinline__ uint dppu(uint v){
  return (uint)__builtin_amdgcn_update_dpp((int)v, (int)v, CTRL, 0xf, 0xf, false);
}
template<int CTRL>
__device__ __forceinline__ void dppkmerge(uint& kl, uint& kh){
  uint okl = dppu<CTRL>(kl);
  uint okh = dppu<CTRL>(kh);
  kmerge(kl, kh, okl, okh);
}

// one block of 512 threads per batch; 8 points/thread held in VGPRs.
// Coords have NO per-thread LDS backing (loaded from global) so the compiler
// cannot rematerialize them via ds_read inside the step loop (round-2/3 bug:
// VGPR_Count=20 proved coords were re-read from LDS every step).
__global__ __launch_bounds__(512, 2) void fps_kernel(const float* __restrict__ xyz,
                                                     float* __restrict__ out_newxyz){
  const int b = blockIdx.x;
  const int t = threadIdx.x;
  __shared__ float4 sxyz[N_PTS];          // 64 KB: winner-coord fetch ONLY
  __shared__ uint   xch[2][8][2];         // per-wave winner keys, parity dbuf
  const float* src = xyz + (size_t)b*N_PTS*3;
  float px[8], py[8], pz[8], dist[8];
  uint nl[8];
#pragma unroll
  for (int i=0;i<8;i++){
    const int p = t + 512*i;              // strided ownership -> coalesced loads
    float x = src[3*p+0], y = src[3*p+1], z = src[3*p+2];
    px[i]=x; py[i]=y; pz[i]=z;
    dist[i]=1e10f; nl[i] = ~(uint)p;
    sxyz[p] = make_float4(x, y, z, 0.f);  // conflict-free ds_write_b128
  }
  __syncthreads();
  float cx, cy, cz;
  { float4 c0 = sxyz[0]; cx=c0.x; cy=c0.y; cz=c0.z; }
  const int w = t >> 6, lane = t & 63;
  float* outx = out_newxyz + (size_t)b*M_PTS*3;
  for (int s = 0; s < M_PTS; ++s){
    if (t == 0){ outx[s*3+0]=cx; outx[s*3+1]=cy; outx[s*3+2]=cz; }
    // A: per-thread dist update (8 pts) + 3-level local tree (key-only)
    uint khv[8];
#pragma unroll
    for (int i=0;i<8;i++){
      float d  = sqdist3(px[i],py[i],pz[i],cx,cy,cz);
      float nd = fminf(dist[i], d);
      dist[i] = nd;
      khv[i] = __float_as_uint(nd);
    }
    uint l0=nl[0], h0=khv[0]; kmerge(l0,h0,nl[1],khv[1]);
    uint l1=nl[2], h1=khv[2]; kmerge(l1,h1,nl[3],khv[3]);
    uint l2=nl[4], h2=khv[4]; kmerge(l2,h2,nl[5],khv[5]);
    uint l3=nl[6], h3=khv[6]; kmerge(l3,h3,nl[7],khv[7]);
    kmerge(l0,h0,l1,h1); kmerge(l2,h2,l3,h3); kmerge(l0,h0,l2,h2);
    uint al=l0, ah=h0;
    // B: 64-lane all-VALU butterfly, key only -> lane 63 = wave winner
    dppkmerge<0x111>(al, ah);   // row_shr:1
    dppkmerge<0x112>(al, ah);   // row_shr:2
    dppkmerge<0x114>(al, ah);   // row_shr:4
    dppkmerge<0x118>(al, ah);   // row_shr:8
    dppkmerge<0x142>(al, ah);   // row_bcast:15
    dppkmerge<0x143>(al, ah);   // row_bcast:31
    // C: cross-wave merge, lane-parallel (8 wave winners)
    const int par = s & 1;
    if (lane == 63){ xch[par][w][0] = al; xch[par][w][1] = ah; }
    __syncthreads();
    uint ckl = xch[par][lane & 7][0];
    uint ckh = xch[par][lane & 7][1];
    dppkmerge<0x111>(ckl, ckh);
    dppkmerge<0x112>(ckl, ckh);
    dppkmerge<0x114>(ckl, ckh);   // lane 7 (each row) = global winner
    uint wkl = (uint)__builtin_amdgcn_readlane((int)ckl, 7);
    uint idx = ~wkl;
    float4 cc = sxyz[idx];        // uniform broadcast read
    cx = cc.x; cy = cc.y; cz = cc.z;
  }
}

// ---------- 2. ball query (exact f32, first-32 in index order) ----------
// 1024 blocks; block = 4 waves handles 16 centroids of one batch
__global__ __launch_bounds__(256) void ballq_kernel(const float* __restrict__ xyz,
                                                    const float* __restrict__ newxyz,
                                                    int* __restrict__ gidx){
  const int blk = blockIdx.x;
  const int b = blk >> 6;
  const int mbase = (blk & 63) * 16;
  __shared__ float sx[N_PTS], sy[N_PTS], sz[N_PTS];
  const float* src = xyz + (size_t)b*N_PTS*3;
  for (int i = threadIdx.x; i < N_PTS*3; i += 256){
    float v = src[i]; int p = i/3, j = i%3;
    (j==0?sx:(j==1?sy:sz))[p] = v;
  }
  __syncthreads();
  const int w = threadIdx.x >> 6, lane = threadIdx.x & 63;
  const float R2 = (float)(0.2*0.2);   // f32(f64 product) — matches reference cast
  for (int mm = w; mm < 16; mm += 4){
    const int m = mbase + mm;
    const float* c = newxyz + ((size_t)b*M_PTS + m)*3;
    float cx = c[0], cy = c[1], cz = c[2];
    int* gout = gidx + ((size_t)b*M_PTS + m)*K_SMP;
    int cnt = 0;
    for (int base = 0; base < N_PTS && cnt < K_SMP; base += 64){
      int p = base + lane;
      float d = sqdist3(sx[p],sy[p],sz[p],cx,cy,cz);
      bool in = (d <= R2);
      unsigned long long mask = __ballot(in);
      int prefix = __popcll(mask & ((1ull << lane) - 1ull));
      int slot = cnt + prefix;
      if (in && slot < K_SMP) gout[slot] = p;
      cnt += __popcll(mask);
    }
    if (cnt < K_SMP){
      int slot = cnt + lane;
      if (slot < K_SMP) gout[slot] = 0;
    }
  }
}

// ---------- 3. conv0: gather + concat + 67->64 matmul (+bias), write bf16 ----------
__global__ __launch_bounds__(256) void conv0_kernel(const float* __restrict__ xyz,
                                                    const float* __restrict__ points,
                                                    const float* __restrict__ newxyz,
                                                    const int* __restrict__ gidx,
                                                    const float* __restrict__ W0,
                                                    const float* __restrict__ b0,
                                                    ushort* __restrict__ x1){
  const int r = blockIdx.x*256 + threadIdx.x;         // 524288 rows
  const int b = r >> 15, m = (r >> 5) & 1023;
  const int g = gidx[r];
  const float* pc = newxyz + ((size_t)(b<<10) + m)*3;
  const float* pp = xyz    + ((size_t)(b<<12) + g)*3;
  float f[67];
  f[0]=pp[0]-pc[0]; f[1]=pp[1]-pc[1]; f[2]=pp[2]-pc[2];
  const float4* prow = (const float4*)(points + (((size_t)(b<<12) + g) << 6));
#pragma unroll
  for (int q=0;q<16;q++){
    float4 v = prow[q];
    f[3+4*q]=v.x; f[4+4*q]=v.y; f[5+4*q]=v.z; f[6+4*q]=v.w;
  }
  float acc[64];
#pragma unroll
  for (int o=0;o<64;o++) acc[o]=b0[o];
#pragma unroll
  for (int o=0;o<64;o++){
    const float* wr = W0 + o*67;
    float a = acc[o];
#pragma unroll
    for (int c=0;c<67;c++) a = fmaf(f[c], wr[c], a);
    acc[o]=a;
  }
  uint4* orow = (uint4*)(x1 + ((size_t)r << 6));
#pragma unroll
  for (int q=0;q<8;q++){
    uint4 v;
    v.x = (uint)f2bf(acc[q*8+0]) | ((uint)f2bf(acc[q*8+1])<<16);
    v.y = (uint)f2bf(acc[q*8+2]) | ((uint)f2bf(acc[q*8+3])<<16);
    v.z = (uint)f2bf(acc[q*8+4]) | ((uint)f2bf(acc[q*8+5])<<16);
    v.w = (uint)f2bf(acc[q*8+6]) | ((uint)f2bf(acc[q*8+7])<<16);
    orow[q]=v;
  }
}

// ---------- stats: per-channel sum & sumsq over all rows ----------
template<int C>
__global__ __launch_bounds__(256) void stats_kernel(const ushort* __restrict__ x,
                                                    float* __restrict__ S,
                                                    float* __restrict__ SS){
  constexpr int RL = 256 / C;
  const int c  = threadIdx.x % C;
  const int rl = threadIdx.x / C;
  const int rows_per_block = NROWS / 256;   // gridDim = 256
  const int r0 = blockIdx.x * rows_per_block;
  const int r1 = r0 + rows_per_block;
  float s = 0.f, ss = 0.f;
  for (int r = r0 + rl; r < r1; r += RL){
    float v = bf2f((uint)x[(size_t)r*C + c]);
    s += v; ss = fmaf(v, v, ss);
  }
  __shared__ float ls[256], lss[256];
  ls[threadIdx.x] = s; lss[threadIdx.x] = ss;
  __syncthreads();
  if (threadIdx.x < C){
    float a = 0.f, q2 = 0.f;
#pragma unroll
    for (int q = 0; q < RL; q++){ a += ls[q*C + c]; q2 += lss[q*C + c]; }
    atomicAdd(&S[c], a); atomicAdd(&SS[c], q2);
  }
}

// ---------- conv1: BN0+ReLU fused on read, 64->64 ----------
__global__ __launch_bounds__(256) void conv1_kernel(const ushort* __restrict__ x1,
                                                    const float* __restrict__ S0,
                                                    const float* __restrict__ SS0,
                                                    const float* __restrict__ g0,
                                                    const float* __restrict__ be0,
                                                    const float* __restrict__ W1,
                                                    const float* __restrict__ b1,
                                                    ushort* __restrict__ x2){
  __shared__ float sc[64], sh[64];
  if (threadIdx.x < 64){
    int c = threadIdx.x;
    float mean = S0[c]*INV_CNT;
    float var  = fmaf(-mean, mean, SS0[c]*INV_CNT);
    float is   = rsqrtf(var + 1e-5f);
    float scv  = g0[c]*is;
    sc[c] = scv; sh[c] = fmaf(-mean, scv, be0[c]);
  }
  __syncthreads();
  const size_t r = (size_t)blockIdx.x*256 + threadIdx.x;
  const uint4* row = (const uint4*)(x1 + (r<<6));
  float f[64];
#pragma unroll
  for (int q=0;q<8;q++){
    uint4 v = row[q];
    f[q*8+0]=bf2f(v.x&0xffffu); f[q*8+1]=bf2f(v.x>>16);
    f[q*8+2]=bf2f(v.y&0xffffu); f[q*8+3]=bf2f(v.y>>16);
    f[q*8+4]=bf2f(v.z&0xffffu); f[q*8+5]=bf2f(v.z>>16);
    f[q*8+6]=bf2f(v.w&0xffffu); f[q*8+7]=bf2f(v.w>>16);
  }
#pragma unroll
  for (int c=0;c<64;c++) f[c] = fmaxf(fmaf(f[c], sc[c], sh[c]), 0.f);
  float acc[64];
#pragma unroll
  for (int o=0;o<64;o++) acc[o]=b1[o];
#pragma unroll
  for (int o=0;o<64;o++){
    const float* wr = W1 + o*64;
    float a = acc[o];
#pragma unroll
    for (int c=0;c<64;c++) a = fmaf(f[c], wr[c], a);
    acc[o]=a;
  }
  uint4* orow = (uint4*)(x2 + (r<<6));
#pragma unroll
  for (int q=0;q<8;q++){
    uint4 v;
    v.x = (uint)f2bf(acc[q*8+0]) | ((uint)f2bf(acc[q*8+1])<<16);
    v.y = (uint)f2bf(acc[q*8+2]) | ((uint)f2bf(acc[q*8+3])<<16);
    v.z = (uint)f2bf(acc[q*8+4]) | ((uint)f2bf(acc[q*8+5])<<16);
    v.w = (uint)f2bf(acc[q*8+6]) | ((uint)f2bf(acc[q*8+7])<<16);
    orow[q]=v;
  }
}

// ---------- conv2: BN1+ReLU fused on read, 64->128 (2 waves share a row set) ----------
__global__ __launch_bounds__(256) void conv2_kernel(const ushort* __restrict__ x2,
                                                    const float* __restrict__ S1,
                                                    const float* __restrict__ SS1,
                                                    const float* __restrict__ g1,
                                                    const float* __restrict__ be1,
                                                    const float* __restrict__ W2,
                                                    const float* __restrict__ b2,
                                                    ushort* __restrict__ x3){
  __shared__ float sc[64], sh[64];
  if (threadIdx.x < 64){
    int c = threadIdx.x;
    float mean = S1[c]*INV_CNT;
    float var  = fmaf(-mean, mean, SS1[c]*INV_CNT);
    float is   = rsqrtf(var + 1e-5f);
    float scv  = g1[c]*is;
    sc[c] = scv; sh[c] = fmaf(-mean, scv, be1[c]);
  }
  __syncthreads();
  const int lane = threadIdx.x & 63;
  const int wv   = threadIdx.x >> 6;
  const size_t r = (size_t)blockIdx.x*128 + (size_t)(wv>>1)*64 + lane;
  const int h = wv & 1;                       // wave-uniform output half
  const uint4* row = (const uint4*)(x2 + (r<<6));
  float f[64];
#pragma unroll
  for (int q=0;q<8;q++){
    uint4 v = row[q];
    f[q*8+0]=bf2f(v.x&0xffffu); f[q*8+1]=bf2f(v.x>>16);
    f[q*8+2]=bf2f(v.y&0xffffu); f[q*8+3]=bf2f(v.y>>16);
    f[q*8+4]=bf2f(v.z&0xffffu); f[q*8+5]=bf2f(v.z>>16);
    f[q*8+6]=bf2f(v.w&0xffffu); f[q*8+7]=bf2f(v.w>>16);
  }
#pragma unroll
  for (int c=0;c<64;c++) f[c] = fmaxf(fmaf(f[c], sc[c], sh[c]), 0.f);
  float acc[64];
#pragma unroll
  for (int o=0;o<64;o++) acc[o]=b2[h*64+o];
#pragma unroll
  for (int o=0;o<64;o++){
    const float* wr = W2 + (size_t)(h*64+o)*64;
    float a = acc[o];
#pragma unroll
    for (int c=0;c<64;c++) a = fmaf(f[c], wr[c], a);
    acc[o]=a;
  }
  uint4* orow = (uint4*)(x3 + ((r<<7) + (size_t)(h<<6)));
#pragma unroll
  for (int q=0;q<8;q++){
    uint4 v;
    v.x = (uint)f2bf(acc[q*8+0]) | ((uint)f2bf(acc[q*8+1])<<16);
    v.y = (uint)f2bf(acc[q*8+2]) | ((uint)f2bf(acc[q*8+3])<<16);
    v.z = (uint)f2bf(acc[q*8+4]) | ((uint)f2bf(acc[q*8+5])<<16);
    v.w = (uint)f2bf(acc[q*8+6]) | ((uint)f2bf(acc[q*8+7])<<16);
    orow[q]=v;
  }
}

// ---------- BN2+ReLU + maxpool over K ----------
__global__ __launch_bounds__(256) void maxpool_kernel(const ushort* __restrict__ x3,
                                                      const float* __restrict__ S2,
                                                      const float* __restrict__ SS2,
                                                      const float* __restrict__ g2,
                                                      const float* __restrict__ be2,
                                                      float* __restrict__ outp){
  const int lane = threadIdx.x & 63, wv = threadIdx.x >> 6;
  const int bm = blockIdx.x*4 + wv;           // 16384 (b,m) groups
  const int c0 = lane*2, c1 = c0+1;
  float mean0 = S2[c0]*INV_CNT;
  float var0  = fmaf(-mean0, mean0, SS2[c0]*INV_CNT);
  float s0 = g2[c0]*rsqrtf(var0+1e-5f);
  float h0 = fmaf(-mean0, s0, be2[c0]);
  float mean1 = S2[c1]*INV_CNT;
  float var1  = fmaf(-mean1, mean1, SS2[c1]*INV_CNT);
  float s1 = g2[c1]*rsqrtf(var1+1e-5f);
  float h1 = fmaf(-mean1, s1, be2[c1]);
  const uint* rb = (const uint*)(x3 + (size_t)bm*K_SMP*128);
  float mx0 = 0.f, mx1 = 0.f;                 // relu floor
#pragma unroll
  for (int k=0;k<K_SMP;k++){
    uint v = rb[k*64 + lane];
    float a0 = bf2f(v & 0xffffu), a1 = bf2f(v >> 16);
    mx0 = fmaxf(mx0, fmaxf(fmaf(a0, s0, h0), 0.f));
    mx1 = fmaxf(mx1, fmaxf(fmaf(a1, s1, h1), 0.f));
  }
  float2* o2 = (float2*)(outp + (size_t)bm*128);
  o2[lane] = make_float2(mx0, mx1);
}

// ---------- launch ----------
extern "C" void kernel_launch(void* const* d_in, const int* in_sizes, int n_in,
                              void* d_out, int out_size, void* d_ws, size_t ws_size,
                              hipStream_t stream){
  const float* xyz    = (const float*)d_in[0];
  const float* points = (const float*)d_in[1];
  const float* w0  = (const float*)d_in[2];
  const float* b0  = (const float*)d_in[3];
  const float* g0  = (const float*)d_in[4];
  const float* be0 = (const float*)d_in[5];
  const float* w1  = (const float*)d_in[6];
  const float* b1  = (const float*)d_in[7];
  const float* g1  = (const float*)d_in[8];
  const float* be1 = (const float*)d_in[9];
  const float* w2  = (const float*)d_in[10];
  const float* b2  = (const float*)d_in[11];
  const float* g2  = (const float*)d_in[12];
  const float* be2 = (const float*)d_in[13];

  float* out      = (float*)d_out;
  float* newxyz   = out;                       // [16,1024,3]
  float* outp     = out + (size_t)B_SZ*M_PTS*3; // [16,1024,128]

  char* ws = (char*)d_ws;
  // ws layout (needs ~205.6 MB):
  //   [0,2MB)          group_idx  int[16][1024][32]
  //   [2MB, +2KB)      stats: S0,SS0,S1,SS1 (64 each), S2,SS2 (128 each)
  //   [4MB, +134MB)    x1 (bf16, 67MB)  then reused by x3 (bf16, 134MB)
  //   [138.4MB,+67MB)  x2 (bf16)
  int*   gidx  = (int*)ws;
  float* stats = (float*)(ws + (2u<<20));
  float* S0 = stats,      *SS0 = stats+64;
  float* S1 = stats+128,  *SS1 = stats+192;
  float* S2 = stats+256,  *SS2 = stats+384;
  ushort* x1 = (ushort*)(ws + (4u<<20));
  ushort* x3 = (ushort*)(ws + (4u<<20));
  ushort* x2 = (ushort*)(ws + (4u<<20) + 134217728u);

  hipMemsetAsync(stats, 0, 512*sizeof(float), stream);
  fps_kernel  <<<B_SZ, 512, 0, stream>>>(xyz, newxyz);
  ballq_kernel<<<1024, 256, 0, stream>>>(xyz, newxyz, gidx);
  conv0_kernel<<<NROWS/256, 256, 0, stream>>>(xyz, points, newxyz, gidx, w0, b0, x1);
  stats_kernel<64><<<256, 256, 0, stream>>>(x1, S0, SS0);
  conv1_kernel<<<NROWS/256, 256, 0, stream>>>(x1, S0, SS0, g0, be0, w1, b1, x2);
  stats_kernel<64><<<256, 256, 0, stream>>>(x2, S1, SS1);
  conv2_kernel<<<NROWS/128, 256, 0, stream>>>(x2, S1, SS1, g1, be1, w2, b2, x3);
  stats_kernel<128><<<256, 256, 0, stream>>>(x3, S2, SS2);
  maxpool_kernel<<<NROWS/128, 256, 0, stream>>>(x3, S2, SS2, g2, be2, outp);
}

// Round 5
// 1765.139 us; speedup vs baseline: 1.6695x; 1.2263x over previous
//
#include <hip/hip_runtime.h>

typedef unsigned int uint;
typedef unsigned short ushort;
typedef unsigned long long u64;
typedef __attribute__((ext_vector_type(2))) float f32x2;

#define N_PTS 4096
#define B_SZ 16
#define M_PTS 1024
#define K_SMP 32
#define NROWS (B_SZ*M_PTS*K_SMP)   /* 524288 */
#define INV_CNT (1.0f/524288.0f)   /* exact: 2^-19 */

// ---------- helpers ----------
__device__ __forceinline__ float sqdist3(float ax,float ay,float az,float bx,float by,float bz){
  // exact-match of numpy/XLA f32: separate sub/mul/add, no FMA contraction
  float dx=__fsub_rn(ax,bx), dy=__fsub_rn(ay,by), dz=__fsub_rn(az,bz);
  return __fadd_rn(__fadd_rn(__fmul_rn(dx,dx),__fmul_rn(dy,dy)),__fmul_rn(dz,dz));
}
__device__ __forceinline__ ushort f2bf(float x){
  uint u = __float_as_uint(x);
  u = (u + 0x7fffu + ((u>>16)&1u)) >> 16;   // RNE
  return (ushort)u;
}
__device__ __forceinline__ float bf2f(uint u){ return __uint_as_float(u<<16); }

// packed f32 pair ops (VOP3P, IEEE RN per element -> bit-exact vs scalar)
__device__ __forceinline__ f32x2 pk_add(f32x2 a, f32x2 b){
  f32x2 d; asm("v_pk_add_f32 %0, %1, %2" : "=v"(d) : "v"(a), "v"(b)); return d;
}
__device__ __forceinline__ f32x2 pk_mul(f32x2 a, f32x2 b){
  f32x2 d; asm("v_pk_mul_f32 %0, %1, %2" : "=v"(d) : "v"(a), "v"(b)); return d;
}

template<int CTRL>
__device__ __forceinline__ uint dppu(uint v){
  return (uint)__builtin_amdgcn_update_dpp((int)v, (int)v, CTRL, 0xf, 0xf, false);
}
template<int CTRL>
__device__ __forceinline__ float dppmaxf(float v){
  float o = __uint_as_float(dppu<CTRL>(__float_as_uint(v)));
  return fmaxf(v, o);
}
template<int CTRL>
__device__ __forceinline__ uint dppminu(uint v){
  uint o = dppu<CTRL>(v);
  return v < o ? v : o;
}

// ---------- 1. FPS: two-phase reduction (f32 wave-max, then masked idx-min) ----------
// 512 threads/batch, 8 points/thread in VGPRs (pairs for packed math).
// Exactness: dist ops are IEEE RN in reference order; argmax tie-break = lowest
// index (phase-2 min over lanes whose max equals the exact wave max).
__global__ __launch_bounds__(512, 2) void fps_kernel(const float* __restrict__ xyz,
                                                     float* __restrict__ out_newxyz){
  const int b = blockIdx.x;
  const int t = threadIdx.x;
  __shared__ float4 sxyz[N_PTS];          // 64 KB: winner-coord broadcast fetch ONLY
  __shared__ __align__(16) uint2 xch[2][8]; // per-wave {max_bits, argidx}, parity dbuf
  const float* src = xyz + (size_t)b*N_PTS*3;
  f32x2 px[4], py[4], pz[4], dist[4];
#pragma unroll
  for (int q=0;q<4;q++){
    const int pa = t + 512*(2*q);
    const int pb = t + 512*(2*q+1);
    float xa=src[3*pa+0], ya=src[3*pa+1], za=src[3*pa+2];
    float xb=src[3*pb+0], yb=src[3*pb+1], zb=src[3*pb+2];
    px[q] = f32x2{xa, xb}; py[q] = f32x2{ya, yb}; pz[q] = f32x2{za, zb};
    dist[q] = f32x2{1e10f, 1e10f};
    sxyz[pa] = make_float4(xa, ya, za, 0.f);
    sxyz[pb] = make_float4(xb, yb, zb, 0.f);
  }
  __syncthreads();
  float cx, cy, cz;
  { float4 c0 = sxyz[0]; cx=c0.x; cy=c0.y; cz=c0.z; }
  const int w = t >> 6, lane = t & 63;
  float* outx = out_newxyz + (size_t)b*M_PTS*3;
  for (int s = 0; s < M_PTS; ++s){
    if (t == 0){ outx[s*3+0]=cx; outx[s*3+1]=cy; outx[s*3+2]=cz; }
    // A: packed dist update: d = (dx*dx + dy*dy) + dz*dz, sub as add of exact-neg
    const f32x2 ncx = f32x2{-cx,-cx}, ncy = f32x2{-cy,-cy}, ncz = f32x2{-cz,-cz};
#pragma unroll
    for (int q=0;q<4;q++){
      f32x2 dx = pk_add(px[q], ncx);
      f32x2 dy = pk_add(py[q], ncy);
      f32x2 dz = pk_add(pz[q], ncz);
      f32x2 d  = pk_add(pk_add(pk_mul(dx,dx), pk_mul(dy,dy)), pk_mul(dz,dz));
      f32x2 nd;
      nd.x = fminf(dist[q].x, d.x);
      nd.y = fminf(dist[q].y, d.y);
      dist[q] = nd;
    }
    // local max of 8
    float m8 = fmaxf(fmaxf(fmaxf(dist[0].x, dist[0].y), fmaxf(dist[1].x, dist[1].y)),
                     fmaxf(fmaxf(dist[2].x, dist[2].y), fmaxf(dist[3].x, dist[3].y)));
    // local argmax -> global point idx, lowest-index priority (iterate high->low)
    uint gb = (uint)t + (7u<<9);
    if (dist[3].x == m8) gb = (uint)t + (6u<<9);
    if (dist[2].y == m8) gb = (uint)t + (5u<<9);
    if (dist[2].x == m8) gb = (uint)t + (4u<<9);
    if (dist[1].y == m8) gb = (uint)t + (3u<<9);
    if (dist[1].x == m8) gb = (uint)t + (2u<<9);
    if (dist[0].y == m8) gb = (uint)t + (1u<<9);
    if (dist[0].x == m8) gb = (uint)t;
    // B1: wave max of m8 (2 ops/stage)
    float wm = m8;
    wm = dppmaxf<0x111>(wm);  // row_shr:1
    wm = dppmaxf<0x112>(wm);  // row_shr:2
    wm = dppmaxf<0x114>(wm);  // row_shr:4
    wm = dppmaxf<0x118>(wm);  // row_shr:8
    wm = dppmaxf<0x142>(wm);  // row_bcast:15
    wm = dppmaxf<0x143>(wm);  // row_bcast:31  -> lane 63 = wave max
    float M = __uint_as_float((uint)__builtin_amdgcn_readlane((int)__float_as_uint(wm), 63));
    // B2: wave min of matching global idx
    uint cand = (m8 == M) ? gb : 0xFFFFFFFFu;
    cand = dppminu<0x111>(cand);
    cand = dppminu<0x112>(cand);
    cand = dppminu<0x114>(cand);
    cand = dppminu<0x118>(cand);
    cand = dppminu<0x142>(cand);
    cand = dppminu<0x143>(cand);
    uint widx = (uint)__builtin_amdgcn_readlane((int)cand, 63);
    // C: cross-wave merge (8 candidates), lane-parallel lexicographic DPP
    const int par = s & 1;
    if (lane == 63) xch[par][w] = make_uint2(__float_as_uint(M), widx);
    __syncthreads();
    uint2 cw = xch[par][lane & 7];
    uint mb = cw.x, mi = cw.y;
    {
      uint ob = dppu<0x111>(mb), oi = dppu<0x111>(mi);
      bool bt = (ob > mb) || (ob == mb && oi < mi);
      mb = bt ? ob : mb; mi = bt ? oi : mi;
      ob = dppu<0x112>(mb); oi = dppu<0x112>(mi);
      bt = (ob > mb) || (ob == mb && oi < mi);
      mb = bt ? ob : mb; mi = bt ? oi : mi;
      ob = dppu<0x114>(mb); oi = dppu<0x114>(mi);
      bt = (ob > mb) || (ob == mb && oi < mi);
      mb = bt ? ob : mb; mi = bt ? oi : mi;
    }
    uint fi = (uint)__builtin_amdgcn_readlane((int)mi, 7);
    float4 cc = sxyz[fi];         // uniform broadcast read
    cx = cc.x; cy = cc.y; cz = cc.z;
  }
}

// ---------- 2. ball query (exact f32, first-32 in index order) ----------
__global__ __launch_bounds__(256) void ballq_kernel(const float* __restrict__ xyz,
                                                    const float* __restrict__ newxyz,
                                                    int* __restrict__ gidx){
  const int blk = blockIdx.x;
  const int b = blk >> 6;
  const int mbase = (blk & 63) * 16;
  __shared__ float sx[N_PTS], sy[N_PTS], sz[N_PTS];
  const float* src = xyz + (size_t)b*N_PTS*3;
  for (int i = threadIdx.x; i < N_PTS*3; i += 256){
    float v = src[i]; int p = i/3, j = i%3;
    (j==0?sx:(j==1?sy:sz))[p] = v;
  }
  __syncthreads();
  const int w = threadIdx.x >> 6, lane = threadIdx.x & 63;
  const float R2 = (float)(0.2*0.2);   // f32(f64 product) — matches reference cast
  for (int mm = w; mm < 16; mm += 4){
    const int m = mbase + mm;
    const float* c = newxyz + ((size_t)b*M_PTS + m)*3;
    float cx = c[0], cy = c[1], cz = c[2];
    int* gout = gidx + ((size_t)b*M_PTS + m)*K_SMP;
    int cnt = 0;
    for (int base = 0; base < N_PTS && cnt < K_SMP; base += 64){
      int p = base + lane;
      float d = sqdist3(sx[p],sy[p],sz[p],cx,cy,cz);
      bool in = (d <= R2);
      unsigned long long mask = __ballot(in);
      int prefix = __popcll(mask & ((1ull << lane) - 1ull));
      int slot = cnt + prefix;
      if (in && slot < K_SMP) gout[slot] = p;
      cnt += __popcll(mask);
    }
    if (cnt < K_SMP){
      int slot = cnt + lane;
      if (slot < K_SMP) gout[slot] = 0;
    }
  }
}

// ---------- 3. conv0: gather + concat + 67->64 matmul (+bias), write bf16 ----------
__global__ __launch_bounds__(256) void conv0_kernel(const float* __restrict__ xyz,
                                                    const float* __restrict__ points,
                                                    const float* __restrict__ newxyz,
                                                    const int* __restrict__ gidx,
                                                    const float* __restrict__ W0,
                                                    const float* __restrict__ b0,
                                                    ushort* __restrict__ x1){
  const int r = blockIdx.x*256 + threadIdx.x;         // 524288 rows
  const int b = r >> 15, m = (r >> 5) & 1023;
  const int g = gidx[r];
  const float* pc = newxyz + ((size_t)(b<<10) + m)*3;
  const float* pp = xyz    + ((size_t)(b<<12) + g)*3;
  float f[67];
  f[0]=pp[0]-pc[0]; f[1]=pp[1]-pc[1]; f[2]=pp[2]-pc[2];
  const float4* prow = (const float4*)(points + (((size_t)(b<<12) + g) << 6));
#pragma unroll
  for (int q=0;q<16;q++){
    float4 v = prow[q];
    f[3+4*q]=v.x; f[4+4*q]=v.y; f[5+4*q]=v.z; f[6+4*q]=v.w;
  }
  float acc[64];
#pragma unroll
  for (int o=0;o<64;o++) acc[o]=b0[o];
#pragma unroll
  for (int o=0;o<64;o++){
    const float* wr = W0 + o*67;
    float a = acc[o];
#pragma unroll
    for (int c=0;c<67;c++) a = fmaf(f[c], wr[c], a);
    acc[o]=a;
  }
  uint4* orow = (uint4*)(x1 + ((size_t)r << 6));
#pragma unroll
  for (int q=0;q<8;q++){
    uint4 v;
    v.x = (uint)f2bf(acc[q*8+0]) | ((uint)f2bf(acc[q*8+1])<<16);
    v.y = (uint)f2bf(acc[q*8+2]) | ((uint)f2bf(acc[q*8+3])<<16);
    v.z = (uint)f2bf(acc[q*8+4]) | ((uint)f2bf(acc[q*8+5])<<16);
    v.w = (uint)f2bf(acc[q*8+6]) | ((uint)f2bf(acc[q*8+7])<<16);
    orow[q]=v;
  }
}

// ---------- stats: per-channel sum & sumsq, vectorized 8 ch/thread ----------
template<int C>
__global__ __launch_bounds__(256) void stats_kernel(const ushort* __restrict__ x,
                                                    float* __restrict__ S,
                                                    float* __restrict__ SS){
  constexpr int GRP = C/8;            // 8-channel groups per row: 8 (C=64) / 16 (C=128)
  constexpr int RL  = 256/GRP;        // row lanes per block: 32 / 16
  const int cg = threadIdx.x % GRP;
  const int rl = threadIdx.x / GRP;
  const int rows_per_block = NROWS / 1024;   // grid = 1024
  const int r0 = blockIdx.x * rows_per_block;
  float s[8], ss[8];
#pragma unroll
  for (int j=0;j<8;j++){ s[j]=0.f; ss[j]=0.f; }
  for (int r = r0 + rl; r < r0 + rows_per_block; r += RL){
    uint4 v = *(const uint4*)(x + (size_t)r*C + cg*8);
    uint d[4] = {v.x, v.y, v.z, v.w};
#pragma unroll
    for (int q=0;q<4;q++){
      float a0 = bf2f(d[q] & 0xffffu), a1 = bf2f(d[q] >> 16);
      s[2*q]   += a0; ss[2*q]   = fmaf(a0, a0, ss[2*q]);
      s[2*q+1] += a1; ss[2*q+1] = fmaf(a1, a1, ss[2*q+1]);
    }
  }
  __shared__ float ls[256][8], lss[256][8];   // 16 KB
#pragma unroll
  for (int j=0;j<8;j++){ ls[threadIdx.x][j]=s[j]; lss[threadIdx.x][j]=ss[j]; }
  __syncthreads();
  if (threadIdx.x < C){
    const int grp = threadIdx.x >> 3, j = threadIdx.x & 7;
    float a = 0.f, q2 = 0.f;
#pragma unroll
    for (int q = 0; q < RL; q++){ a += ls[q*GRP + grp][j]; q2 += lss[q*GRP + grp][j]; }
    atomicAdd(&S[threadIdx.x], a); atomicAdd(&SS[threadIdx.x], q2);
  }
}

// ---------- conv1: BN0+ReLU fused on read, 64->64 ----------
__global__ __launch_bounds__(256) void conv1_kernel(const ushort* __restrict__ x1,
                                                    const float* __restrict__ S0,
                                                    const float* __restrict__ SS0,
                                                    const float* __restrict__ g0,
                                                    const float* __restrict__ be0,
                                                    const float* __restrict__ W1,
                                                    const float* __restrict__ b1,
                                                    ushort* __restrict__ x2){
  __shared__ float sc[64], sh[64];
  if (threadIdx.x < 64){
    int c = threadIdx.x;
    float mean = S0[c]*INV_CNT;
    float var  = fmaf(-mean, mean, SS0[c]*INV_CNT);
    float is   = rsqrtf(var + 1e-5f);
    float scv  = g0[c]*is;
    sc[c] = scv; sh[c] = fmaf(-mean, scv, be0[c]);
  }
  __syncthreads();
  const size_t r = (size_t)blockIdx.x*256 + threadIdx.x;
  const uint4* row = (const uint4*)(x1 + (r<<6));
  float f[64];
#pragma unroll
  for (int q=0;q<8;q++){
    uint4 v = row[q];
    f[q*8+0]=bf2f(v.x&0xffffu); f[q*8+1]=bf2f(v.x>>16);
    f[q*8+2]=bf2f(v.y&0xffffu); f[q*8+3]=bf2f(v.y>>16);
    f[q*8+4]=bf2f(v.z&0xffffu); f[q*8+5]=bf2f(v.z>>16);
    f[q*8+6]=bf2f(v.w&0xffffu); f[q*8+7]=bf2f(v.w>>16);
  }
#pragma unroll
  for (int c=0;c<64;c++) f[c] = fmaxf(fmaf(f[c], sc[c], sh[c]), 0.f);
  float acc[64];
#pragma unroll
  for (int o=0;o<64;o++) acc[o]=b1[o];
#pragma unroll
  for (int o=0;o<64;o++){
    const float* wr = W1 + o*64;
    float a = acc[o];
#pragma unroll
    for (int c=0;c<64;c++) a = fmaf(f[c], wr[c], a);
    acc[o]=a;
  }
  uint4* orow = (uint4*)(x2 + (r<<6));
#pragma unroll
  for (int q=0;q<8;q++){
    uint4 v;
    v.x = (uint)f2bf(acc[q*8+0]) | ((uint)f2bf(acc[q*8+1])<<16);
    v.y = (uint)f2bf(acc[q*8+2]) | ((uint)f2bf(acc[q*8+3])<<16);
    v.z = (uint)f2bf(acc[q*8+4]) | ((uint)f2bf(acc[q*8+5])<<16);
    v.w = (uint)f2bf(acc[q*8+6]) | ((uint)f2bf(acc[q*8+7])<<16);
    orow[q]=v;
  }
}

// ---------- conv2: BN1+ReLU fused on read, 64->128 ----------
__global__ __launch_bounds__(256) void conv2_kernel(const ushort* __restrict__ x2,
                                                    const float* __restrict__ S1,
                                                    const float* __restrict__ SS1,
                                                    const float* __restrict__ g1,
                                                    const float* __restrict__ be1,
                                                    const float* __restrict__ W2,
                                                    const float* __restrict__ b2,
                                                    ushort* __restrict__ x3){
  __shared__ float sc[64], sh[64];
  if (threadIdx.x < 64){
    int c = threadIdx.x;
    float mean = S1[c]*INV_CNT;
    float var  = fmaf(-mean, mean, SS1[c]*INV_CNT);
    float is   = rsqrtf(var + 1e-5f);
    float scv  = g1[c]*is;
    sc[c] = scv; sh[c] = fmaf(-mean, scv, be1[c]);
  }
  __syncthreads();
  const int lane = threadIdx.x & 63;
  const int wv   = threadIdx.x >> 6;
  const size_t r = (size_t)blockIdx.x*128 + (size_t)(wv>>1)*64 + lane;
  const int h = wv & 1;                       // wave-uniform output half
  const uint4* row = (const uint4*)(x2 + (r<<6));
  float f[64];
#pragma unroll
  for (int q=0;q<8;q++){
    uint4 v = row[q];
    f[q*8+0]=bf2f(v.x&0xffffu); f[q*8+1]=bf2f(v.x>>16);
    f[q*8+2]=bf2f(v.y&0xffffu); f[q*8+3]=bf2f(v.y>>16);
    f[q*8+4]=bf2f(v.z&0xffffu); f[q*8+5]=bf2f(v.z>>16);
    f[q*8+6]=bf2f(v.w&0xffffu); f[q*8+7]=bf2f(v.w>>16);
  }
#pragma unroll
  for (int c=0;c<64;c++) f[c] = fmaxf(fmaf(f[c], sc[c], sh[c]), 0.f);
  float acc[64];
#pragma unroll
  for (int o=0;o<64;o++) acc[o]=b2[h*64+o];
#pragma unroll
  for (int o=0;o<64;o++){
    const float* wr = W2 + (size_t)(h*64+o)*64;
    float a = acc[o];
#pragma unroll
    for (int c=0;c<64;c++) a = fmaf(f[c], wr[c], a);
    acc[o]=a;
  }
  uint4* orow = (uint4*)(x3 + ((r<<7) + (size_t)(h<<6)));
#pragma unroll
  for (int q=0;q<8;q++){
    uint4 v;
    v.x = (uint)f2bf(acc[q*8+0]) | ((uint)f2bf(acc[q*8+1])<<16);
    v.y = (uint)f2bf(acc[q*8+2]) | ((uint)f2bf(acc[q*8+3])<<16);
    v.z = (uint)f2bf(acc[q*8+4]) | ((uint)f2bf(acc[q*8+5])<<16);
    v.w = (uint)f2bf(acc[q*8+6]) | ((uint)f2bf(acc[q*8+7])<<16);
    orow[q]=v;
  }
}

// ---------- BN2+ReLU + maxpool over K ----------
__global__ __launch_bounds__(256) void maxpool_kernel(const ushort* __restrict__ x3,
                                                      const float* __restrict__ S2,
                                                      const float* __restrict__ SS2,
                                                      const float* __restrict__ g2,
                                                      const float* __restrict__ be2,
                                                      float* __restrict__ outp){
  const int lane = threadIdx.x & 63, wv = threadIdx.x >> 6;
  const int bm = blockIdx.x*4 + wv;           // 16384 (b,m) groups
  const int c0 = lane*2, c1 = c0+1;
  float mean0 = S2[c0]*INV_CNT;
  float var0  = fmaf(-mean0, mean0, SS2[c0]*INV_CNT);
  float s0 = g2[c0]*rsqrtf(var0+1e-5f);
  float h0 = fmaf(-mean0, s0, be2[c0]);
  float mean1 = S2[c1]*INV_CNT;
  float var1  = fmaf(-mean1, mean1, SS2[c1]*INV_CNT);
  float s1 = g2[c1]*rsqrtf(var1+1e-5f);
  float h1 = fmaf(-mean1, s1, be2[c1]);
  const uint* rb = (const uint*)(x3 + (size_t)bm*K_SMP*128);
  float mx0 = 0.f, mx1 = 0.f;                 // relu floor
#pragma unroll
  for (int k=0;k<K_SMP;k++){
    uint v = rb[k*64 + lane];
    float a0 = bf2f(v & 0xffffu), a1 = bf2f(v >> 16);
    mx0 = fmaxf(mx0, fmaxf(fmaf(a0, s0, h0), 0.f));
    mx1 = fmaxf(mx1, fmaxf(fmaf(a1, s1, h1), 0.f));
  }
  float2* o2 = (float2*)(outp + (size_t)bm*128);
  o2[lane] = make_float2(mx0, mx1);
}

// ---------- launch ----------
extern "C" void kernel_launch(void* const* d_in, const int* in_sizes, int n_in,
                              void* d_out, int out_size, void* d_ws, size_t ws_size,
                              hipStream_t stream){
  const float* xyz    = (const float*)d_in[0];
  const float* points = (const float*)d_in[1];
  const float* w0  = (const float*)d_in[2];
  const float* b0  = (const float*)d_in[3];
  const float* g0  = (const float*)d_in[4];
  const float* be0 = (const float*)d_in[5];
  const float* w1  = (const float*)d_in[6];
  const float* b1  = (const float*)d_in[7];
  const float* g1  = (const float*)d_in[8];
  const float* be1 = (const float*)d_in[9];
  const float* w2  = (const float*)d_in[10];
  const float* b2  = (const float*)d_in[11];
  const float* g2  = (const float*)d_in[12];
  const float* be2 = (const float*)d_in[13];

  float* out      = (float*)d_out;
  float* newxyz   = out;                        // [16,1024,3]
  float* outp     = out + (size_t)B_SZ*M_PTS*3; // [16,1024,128]

  char* ws = (char*)d_ws;
  int*   gidx  = (int*)ws;
  float* stats = (float*)(ws + (2u<<20));
  float* S0 = stats,      *SS0 = stats+64;
  float* S1 = stats+128,  *SS1 = stats+192;
  float* S2 = stats+256,  *SS2 = stats+384;
  ushort* x1 = (ushort*)(ws + (4u<<20));
  ushort* x3 = (ushort*)(ws + (4u<<20));
  ushort* x2 = (ushort*)(ws + (4u<<20) + 134217728u);

  hipMemsetAsync(stats, 0, 512*sizeof(float), stream);
  fps_kernel  <<<B_SZ, 512, 0, stream>>>(xyz, newxyz);
  ballq_kernel<<<1024, 256, 0, stream>>>(xyz, newxyz, gidx);
  conv0_kernel<<<NROWS/256, 256, 0, stream>>>(xyz, points, newxyz, gidx, w0, b0, x1);
  stats_kernel<64><<<1024, 256, 0, stream>>>(x1, S0, SS0);
  conv1_kernel<<<NROWS/256, 256, 0, stream>>>(x1, S0, SS0, g0, be0, w1, b1, x2);
  stats_kernel<64><<<1024, 256, 0, stream>>>(x2, S1, SS1);
  conv2_kernel<<<NROWS/128, 256, 0, stream>>>(x2, S1, SS1, g1, be1, w2, b2, x3);
  stats_kernel<128><<<1024, 256, 0, stream>>>(x3, S2, SS2);
  maxpool_kernel<<<NROWS/128, 256, 0, stream>>>(x3, S2, SS2, g2, be2, outp);
}